// Round 7
// baseline (652.259 us; speedup 1.0000x reference)
//
#include <hip/hip_runtime.h>

// GCN encoder, fused gather formulation + fine-bucket CSR build.
// Measured models (MI355X):
//  - same-address atomic chain ~184ns/op (r3) -> BSH=2: 64/addr, ~12us floor.
//  - 1-output/thread dense = latency-stalled (r5) -> 4x4 register tiling.
//  - big LDS kills occupancy (r6: 50.7KB -> 3 blocks/CU, occ 26%) -> no x
//    staging; read x direct from global (L1 broadcast), LDS = h0 only (17.4KB).
// Pipeline (9 dispatches):
//   zero | bucket_fill | bscan | build_csr
//   K0 : h0=x@Win+b -> {out = allbias + h0@Ws0, hwA=(h0@Wg0)*dinv}
//   GT1: gather(hwA)->h1 -> {out+=h1@Ws1, hwB=(h1@Wg1)*dinv}
//   GT2: gather(hwB)->h2 -> {out+=h2@Ws2, hwA=(h2@Wg2)*dinv}
//   GT3: gather(hwA)->h3 -> hwB32=(h3@Wl)*dinv
//   GO : out += dinv * gather32(hwB32)
// Identity: gcn(h)[v] = dinv[v] * sum_{s in nbr(v) u {v}} (hW*dinv)[s] + b

#define HID 64
#define LAT 32
#define BSH 2          // 4 nodes per bucket
#define BCAP 160       // mean 64, +12 sigma margin

static inline int cdiv(long long a, long long b) { return (int)((a + b - 1) / b); }

// ---------------- CSR build ----------------

__global__ void zero_kernel(int* __restrict__ p, int n) {
    int i = blockIdx.x * blockDim.x + threadIdx.x;
    if (i < n) p[i] = 0;
}

__global__ void bucket_fill_kernel(const int* __restrict__ src, const int* __restrict__ dst,
                                   int* __restrict__ bcur, unsigned* __restrict__ bbuf, int E) {
    int e = blockIdx.x * blockDim.x + threadIdx.x;
    if (e >= E) return;
    int s = src[e], d = dst[e];
    int b = d >> BSH;
    int pos = atomicAdd(&bcur[b], 1);
    if (pos < BCAP)
        bbuf[(size_t)b * BCAP + pos] = ((unsigned)(d & ((1 << BSH) - 1)) << 17) | (unsigned)s;
}

__global__ void bscan_kernel(const int* __restrict__ bcur, int* __restrict__ bstart, int nb) {
    __shared__ int s[1024];
    __shared__ int carry;
    int t = threadIdx.x;
    if (t == 0) carry = 0;
    __syncthreads();
    for (int base = 0; base < nb; base += 1024) {
        int i = base + t;
        int v = (i < nb) ? bcur[i] : 0;
        s[t] = v;
        __syncthreads();
        for (int off = 1; off < 1024; off <<= 1) {
            int x = (t >= off) ? s[t - off] : 0;
            __syncthreads();
            s[t] += x;
            __syncthreads();
        }
        if (i < nb) bstart[i] = carry + s[t] - v;
        __syncthreads();
        if (t == 1023) carry += s[1023];
        __syncthreads();
    }
}

__global__ void build_csr_kernel(const int* __restrict__ bcur, const int* __restrict__ bstart,
                                 const unsigned* __restrict__ bbuf, int* __restrict__ csr,
                                 int* __restrict__ rowstart, float* __restrict__ dinv,
                                 int n, int E) {
    __shared__ int lcount[1 << BSH], lpre[1 << BSH], lcur[1 << BSH];
    int b = blockIdx.x, t = threadIdx.x;
    int cnt = bcur[b];
    if (cnt > BCAP) cnt = BCAP;
    int bst = bstart[b];
    size_t ebase = (size_t)b * BCAP;

    if (t < (1 << BSH)) lcount[t] = 0;
    __syncthreads();

    unsigned rec[2];
    int nrec = 0;
    for (int i = t; i < cnt; i += 128) {
        unsigned p = bbuf[ebase + i];
        rec[nrec++] = p;
        atomicAdd(&lcount[p >> 17], 1);
    }
    __syncthreads();

    if (t == 0) {
        int run = 0;
        for (int k = 0; k < (1 << BSH); ++k) {
            lpre[k] = run;
            lcur[k] = run;
            run += lcount[k];
        }
    }
    __syncthreads();

    if (t < (1 << BSH)) {
        int v = (b << BSH) + t;
        if (v < n) {
            rowstart[v] = bst + lpre[t];
            dinv[v] = rsqrtf((float)(lcount[t] + 1));
        }
    }
    if (b == 0 && t == 0) rowstart[n] = E;

    for (int j = 0; j < nrec; ++j) {
        unsigned p = rec[j];
        int pos = bst + atomicAdd(&lcur[p >> 17], 1);
        csr[pos] = (int)(p & 0x1FFFFu);
    }
}

// ---------------- K0: input layer, fused, 4x4 tiled, no x staging ----------------
// 64 rows/block, 256 thr. Phase1: h0 = x@Win + bin, x read direct from global
// (threads sharing a row broadcast via L1). Phase2a: hw=(h0@Wg0)*dinv.
// Phase2b: out = (bl+sum bs) + h0@Ws0 (store, fuses out_init).

__global__ __launch_bounds__(256) void input_fused_kernel(
        const float* __restrict__ x, const float* __restrict__ Win,
        const float* __restrict__ bin, const float* __restrict__ Wg0,
        const float* __restrict__ Ws0, const float* __restrict__ dinv,
        const float* __restrict__ bl, const float* __restrict__ bs,
        float* __restrict__ hw, float* __restrict__ out, int n) {
    __shared__ float h0[64 * 68];   // stride 68: 2-way bank alias (free), 16B rows
    int t = threadIdx.x;
    int vbase = blockIdx.x * 64;
    int rg = t >> 4, lc = t & 15;

    int r0 = vbase + rg * 4;
    const float* xp0 = x + (size_t)(r0 + 0 < n ? r0 + 0 : n - 1) * 128;
    const float* xp1 = x + (size_t)(r0 + 1 < n ? r0 + 1 : n - 1) * 128;
    const float* xp2 = x + (size_t)(r0 + 2 < n ? r0 + 2 : n - 1) * 128;
    const float* xp3 = x + (size_t)(r0 + 3 < n ? r0 + 3 : n - 1) * 128;

    {
        float4 b4 = *(const float4*)&bin[4 * lc];
        float4 a0 = b4, a1 = b4, a2 = b4, a3 = b4;
#pragma unroll 4
        for (int k = 0; k < 128; k += 4) {
            float4 x0 = *(const float4*)&xp0[k];
            float4 x1 = *(const float4*)&xp1[k];
            float4 x2 = *(const float4*)&xp2[k];
            float4 x3 = *(const float4*)&xp3[k];
            float4 w;
            w = *(const float4*)&Win[(k + 0) * 64 + 4 * lc];
            a0.x = fmaf(x0.x, w.x, a0.x); a0.y = fmaf(x0.x, w.y, a0.y);
            a0.z = fmaf(x0.x, w.z, a0.z); a0.w = fmaf(x0.x, w.w, a0.w);
            a1.x = fmaf(x1.x, w.x, a1.x); a1.y = fmaf(x1.x, w.y, a1.y);
            a1.z = fmaf(x1.x, w.z, a1.z); a1.w = fmaf(x1.x, w.w, a1.w);
            a2.x = fmaf(x2.x, w.x, a2.x); a2.y = fmaf(x2.x, w.y, a2.y);
            a2.z = fmaf(x2.x, w.z, a2.z); a2.w = fmaf(x2.x, w.w, a2.w);
            a3.x = fmaf(x3.x, w.x, a3.x); a3.y = fmaf(x3.x, w.y, a3.y);
            a3.z = fmaf(x3.x, w.z, a3.z); a3.w = fmaf(x3.x, w.w, a3.w);
            w = *(const float4*)&Win[(k + 1) * 64 + 4 * lc];
            a0.x = fmaf(x0.y, w.x, a0.x); a0.y = fmaf(x0.y, w.y, a0.y);
            a0.z = fmaf(x0.y, w.z, a0.z); a0.w = fmaf(x0.y, w.w, a0.w);
            a1.x = fmaf(x1.y, w.x, a1.x); a1.y = fmaf(x1.y, w.y, a1.y);
            a1.z = fmaf(x1.y, w.z, a1.z); a1.w = fmaf(x1.y, w.w, a1.w);
            a2.x = fmaf(x2.y, w.x, a2.x); a2.y = fmaf(x2.y, w.y, a2.y);
            a2.z = fmaf(x2.y, w.z, a2.z); a2.w = fmaf(x2.y, w.w, a2.w);
            a3.x = fmaf(x3.y, w.x, a3.x); a3.y = fmaf(x3.y, w.y, a3.y);
            a3.z = fmaf(x3.y, w.z, a3.z); a3.w = fmaf(x3.y, w.w, a3.w);
            w = *(const float4*)&Win[(k + 2) * 64 + 4 * lc];
            a0.x = fmaf(x0.z, w.x, a0.x); a0.y = fmaf(x0.z, w.y, a0.y);
            a0.z = fmaf(x0.z, w.z, a0.z); a0.w = fmaf(x0.z, w.w, a0.w);
            a1.x = fmaf(x1.z, w.x, a1.x); a1.y = fmaf(x1.z, w.y, a1.y);
            a1.z = fmaf(x1.z, w.z, a1.z); a1.w = fmaf(x1.z, w.w, a1.w);
            a2.x = fmaf(x2.z, w.x, a2.x); a2.y = fmaf(x2.z, w.y, a2.y);
            a2.z = fmaf(x2.z, w.z, a2.z); a2.w = fmaf(x2.z, w.w, a2.w);
            a3.x = fmaf(x3.z, w.x, a3.x); a3.y = fmaf(x3.z, w.y, a3.y);
            a3.z = fmaf(x3.z, w.z, a3.z); a3.w = fmaf(x3.z, w.w, a3.w);
            w = *(const float4*)&Win[(k + 3) * 64 + 4 * lc];
            a0.x = fmaf(x0.w, w.x, a0.x); a0.y = fmaf(x0.w, w.y, a0.y);
            a0.z = fmaf(x0.w, w.z, a0.z); a0.w = fmaf(x0.w, w.w, a0.w);
            a1.x = fmaf(x1.w, w.x, a1.x); a1.y = fmaf(x1.w, w.y, a1.y);
            a1.z = fmaf(x1.w, w.z, a1.z); a1.w = fmaf(x1.w, w.w, a1.w);
            a2.x = fmaf(x2.w, w.x, a2.x); a2.y = fmaf(x2.w, w.y, a2.y);
            a2.z = fmaf(x2.w, w.z, a2.z); a2.w = fmaf(x2.w, w.w, a2.w);
            a3.x = fmaf(x3.w, w.x, a3.x); a3.y = fmaf(x3.w, w.y, a3.y);
            a3.z = fmaf(x3.w, w.z, a3.z); a3.w = fmaf(x3.w, w.w, a3.w);
        }
        *(float4*)&h0[(rg * 4 + 0) * 68 + 4 * lc] = a0;
        *(float4*)&h0[(rg * 4 + 1) * 68 + 4 * lc] = a1;
        *(float4*)&h0[(rg * 4 + 2) * 68 + 4 * lc] = a2;
        *(float4*)&h0[(rg * 4 + 3) * 68 + 4 * lc] = a3;
    }
    __syncthreads();

    // Phase2a: hw = (h0 @ Wg0) * dinv
    {
        float4 a0, a1, a2, a3;
        a0 = a1 = a2 = a3 = make_float4(0.f, 0.f, 0.f, 0.f);
#pragma unroll 8
        for (int k = 0; k < 64; ++k) {
            float4 w = *(const float4*)&Wg0[k * 64 + 4 * lc];
            float x0 = h0[(rg * 4 + 0) * 68 + k];
            float x1 = h0[(rg * 4 + 1) * 68 + k];
            float x2 = h0[(rg * 4 + 2) * 68 + k];
            float x3 = h0[(rg * 4 + 3) * 68 + k];
            a0.x = fmaf(x0, w.x, a0.x); a0.y = fmaf(x0, w.y, a0.y);
            a0.z = fmaf(x0, w.z, a0.z); a0.w = fmaf(x0, w.w, a0.w);
            a1.x = fmaf(x1, w.x, a1.x); a1.y = fmaf(x1, w.y, a1.y);
            a1.z = fmaf(x1, w.z, a1.z); a1.w = fmaf(x1, w.w, a1.w);
            a2.x = fmaf(x2, w.x, a2.x); a2.y = fmaf(x2, w.y, a2.y);
            a2.z = fmaf(x2, w.z, a2.z); a2.w = fmaf(x2, w.w, a2.w);
            a3.x = fmaf(x3, w.x, a3.x); a3.y = fmaf(x3, w.y, a3.y);
            a3.z = fmaf(x3, w.z, a3.z); a3.w = fmaf(x3, w.w, a3.w);
        }
#pragma unroll
        for (int r = 0; r < 4; ++r) {
            int v = vbase + rg * 4 + r;
            if (v < n) {
                float di = dinv[v];
                float4 a = (r == 0) ? a0 : (r == 1) ? a1 : (r == 2) ? a2 : a3;
                a.x *= di; a.y *= di; a.z *= di; a.w *= di;
                *(float4*)&hw[(size_t)v * 64 + 4 * lc] = a;
            }
        }
    }

    // Phase2b: out = (bl + sum bs) + h0 @ Ws0   (store, no RMW)
    {
        int sg = t >> 3, sc = t & 7;
        float4 bb = *(const float4*)&bl[4 * sc];
        float4 q0 = *(const float4*)&bs[4 * sc];
        float4 q1 = *(const float4*)&bs[LAT + 4 * sc];
        float4 q2 = *(const float4*)&bs[2 * LAT + 4 * sc];
        bb.x += q0.x + q1.x + q2.x; bb.y += q0.y + q1.y + q2.y;
        bb.z += q0.z + q1.z + q2.z; bb.w += q0.w + q1.w + q2.w;
        float4 a0 = bb, a1 = bb;
#pragma unroll 8
        for (int k = 0; k < 64; ++k) {
            float4 w = *(const float4*)&Ws0[k * 32 + 4 * sc];
            float x0 = h0[(sg * 2 + 0) * 68 + k];
            float x1 = h0[(sg * 2 + 1) * 68 + k];
            a0.x = fmaf(x0, w.x, a0.x); a0.y = fmaf(x0, w.y, a0.y);
            a0.z = fmaf(x0, w.z, a0.z); a0.w = fmaf(x0, w.w, a0.w);
            a1.x = fmaf(x1, w.x, a1.x); a1.y = fmaf(x1, w.y, a1.y);
            a1.z = fmaf(x1, w.z, a1.z); a1.w = fmaf(x1, w.w, a1.w);
        }
#pragma unroll
        for (int r = 0; r < 2; ++r) {
            int v = vbase + sg * 2 + r;
            if (v < n)
                *(float4*)&out[(size_t)v * 32 + 4 * sc] = (r == 0) ? a0 : a1;
        }
    }
}

// ---------------- fused gather + transform, 64 nodes/block ----------------

template <bool LAST>
__global__ __launch_bounds__(256) void gather_transform_kernel(
        const int* __restrict__ rowstart, const int* __restrict__ csr,
        const float* __restrict__ dinv, const float* __restrict__ hwin,
        const float* __restrict__ bias, const float* __restrict__ Wg,
        const float* __restrict__ Ws, float* __restrict__ hwout,
        float* __restrict__ out, int n) {
    __shared__ float hL[64 * 68];
    int t = threadIdx.x;
    int vbase = blockIdx.x * 64;
    int ns = t >> 4, lc = t & 15;

    float4 b4 = *(const float4*)&bias[4 * lc];
#pragma unroll
    for (int b = 0; b < 4; ++b) {
        int row = b * 16 + ns;
        int v = vbase + row;
        if (v < n) {
            int beg = rowstart[v];
            int end = rowstart[v + 1];
            float di = dinv[v];
            float4 acc = *(const float4*)&hwin[(size_t)v * 64 + 4 * lc];  // self
            const float* base = hwin + 4 * lc;
            int e = beg;
            for (; e + 3 < end; e += 4) {
                int s0 = csr[e], s1 = csr[e + 1], s2 = csr[e + 2], s3 = csr[e + 3];
                float4 g0 = *(const float4*)&base[(size_t)s0 * 64];
                float4 g1 = *(const float4*)&base[(size_t)s1 * 64];
                float4 g2 = *(const float4*)&base[(size_t)s2 * 64];
                float4 g3 = *(const float4*)&base[(size_t)s3 * 64];
                acc.x += (g0.x + g1.x) + (g2.x + g3.x);
                acc.y += (g0.y + g1.y) + (g2.y + g3.y);
                acc.z += (g0.z + g1.z) + (g2.z + g3.z);
                acc.w += (g0.w + g1.w) + (g2.w + g3.w);
            }
            for (; e < end; ++e) {
                float4 g0 = *(const float4*)&base[(size_t)csr[e] * 64];
                acc.x += g0.x; acc.y += g0.y; acc.z += g0.z; acc.w += g0.w;
            }
            float4 h;
            h.x = di * acc.x + b4.x; h.x = h.x > 0.f ? h.x : 0.2f * h.x;
            h.y = di * acc.y + b4.y; h.y = h.y > 0.f ? h.y : 0.2f * h.y;
            h.z = di * acc.z + b4.z; h.z = h.z > 0.f ? h.z : 0.2f * h.z;
            h.w = di * acc.w + b4.w; h.w = h.w > 0.f ? h.w : 0.2f * h.w;
            *(float4*)&hL[row * 68 + 4 * lc] = h;
        }
    }
    __syncthreads();

    if (!LAST) {
        int rg = t >> 4;
        float4 a0, a1, a2, a3;
        a0 = a1 = a2 = a3 = make_float4(0.f, 0.f, 0.f, 0.f);
#pragma unroll 8
        for (int k = 0; k < 64; ++k) {
            float4 w = *(const float4*)&Wg[k * 64 + 4 * lc];
            float x0 = hL[(rg * 4 + 0) * 68 + k];
            float x1 = hL[(rg * 4 + 1) * 68 + k];
            float x2 = hL[(rg * 4 + 2) * 68 + k];
            float x3 = hL[(rg * 4 + 3) * 68 + k];
            a0.x = fmaf(x0, w.x, a0.x); a0.y = fmaf(x0, w.y, a0.y);
            a0.z = fmaf(x0, w.z, a0.z); a0.w = fmaf(x0, w.w, a0.w);
            a1.x = fmaf(x1, w.x, a1.x); a1.y = fmaf(x1, w.y, a1.y);
            a1.z = fmaf(x1, w.z, a1.z); a1.w = fmaf(x1, w.w, a1.w);
            a2.x = fmaf(x2, w.x, a2.x); a2.y = fmaf(x2, w.y, a2.y);
            a2.z = fmaf(x2, w.z, a2.z); a2.w = fmaf(x2, w.w, a2.w);
            a3.x = fmaf(x3, w.x, a3.x); a3.y = fmaf(x3, w.y, a3.y);
            a3.z = fmaf(x3, w.z, a3.z); a3.w = fmaf(x3, w.w, a3.w);
        }
#pragma unroll
        for (int r = 0; r < 4; ++r) {
            int v = vbase + rg * 4 + r;
            if (v < n) {
                float di = dinv[v];
                float4 a = (r == 0) ? a0 : (r == 1) ? a1 : (r == 2) ? a2 : a3;
                a.x *= di; a.y *= di; a.z *= di; a.w *= di;
                *(float4*)&hwout[(size_t)v * 64 + 4 * lc] = a;
            }
        }

        int sg = t >> 3, sc = t & 7;
        float4 s0, s1;
        s0 = s1 = make_float4(0.f, 0.f, 0.f, 0.f);
#pragma unroll 8
        for (int k = 0; k < 64; ++k) {
            float4 w = *(const float4*)&Ws[k * 32 + 4 * sc];
            float x0 = hL[(sg * 2 + 0) * 68 + k];
            float x1 = hL[(sg * 2 + 1) * 68 + k];
            s0.x = fmaf(x0, w.x, s0.x); s0.y = fmaf(x0, w.y, s0.y);
            s0.z = fmaf(x0, w.z, s0.z); s0.w = fmaf(x0, w.w, s0.w);
            s1.x = fmaf(x1, w.x, s1.x); s1.y = fmaf(x1, w.y, s1.y);
            s1.z = fmaf(x1, w.z, s1.z); s1.w = fmaf(x1, w.w, s1.w);
        }
#pragma unroll
        for (int r = 0; r < 2; ++r) {
            int v = vbase + sg * 2 + r;
            if (v < n) {
                float4 a = (r == 0) ? s0 : s1;
                float4* op = (float4*)(out + (size_t)v * 32 + 4 * sc);
                float4 o = *op;
                o.x += a.x; o.y += a.y; o.z += a.z; o.w += a.w;
                *op = o;
            }
        }
    } else {
        int sg = t >> 3, sc = t & 7;
        float4 s0, s1;
        s0 = s1 = make_float4(0.f, 0.f, 0.f, 0.f);
#pragma unroll 8
        for (int k = 0; k < 64; ++k) {
            float4 w = *(const float4*)&Ws[k * 32 + 4 * sc];  // Ws == Wl
            float x0 = hL[(sg * 2 + 0) * 68 + k];
            float x1 = hL[(sg * 2 + 1) * 68 + k];
            s0.x = fmaf(x0, w.x, s0.x); s0.y = fmaf(x0, w.y, s0.y);
            s0.z = fmaf(x0, w.z, s0.z); s0.w = fmaf(x0, w.w, s0.w);
            s1.x = fmaf(x1, w.x, s1.x); s1.y = fmaf(x1, w.y, s1.y);
            s1.z = fmaf(x1, w.z, s1.z); s1.w = fmaf(x1, w.w, s1.w);
        }
#pragma unroll
        for (int r = 0; r < 2; ++r) {
            int v = vbase + sg * 2 + r;
            if (v < n) {
                float di = dinv[v];
                float4 a = (r == 0) ? s0 : s1;
                a.x *= di; a.y *= di; a.z *= di; a.w *= di;
                *(float4*)&hwout[(size_t)v * 32 + 4 * sc] = a;
            }
        }
    }
}

// ---------------- final gather into output (32 ch, 8 lanes/node) ----------------

__global__ __launch_bounds__(256) void gather_out_kernel(
        const int* __restrict__ rowstart, const int* __restrict__ csr,
        const float* __restrict__ dinv, const float* __restrict__ hwl,
        float* __restrict__ out, int n) {
    int t = threadIdx.x;
    int lr = t >> 3, lc = t & 7;
    int v = blockIdx.x * 32 + lr;
    if (v >= n) return;
    int beg = rowstart[v], end = rowstart[v + 1];
    float4 acc = *(const float4*)&hwl[(size_t)v * 32 + 4 * lc];
    const float* base = hwl + 4 * lc;
    int e = beg;
    for (; e + 3 < end; e += 4) {
        int s0 = csr[e], s1 = csr[e + 1], s2 = csr[e + 2], s3 = csr[e + 3];
        float4 a0 = *(const float4*)&base[(size_t)s0 * 32];
        float4 a1 = *(const float4*)&base[(size_t)s1 * 32];
        float4 a2 = *(const float4*)&base[(size_t)s2 * 32];
        float4 a3 = *(const float4*)&base[(size_t)s3 * 32];
        acc.x += (a0.x + a1.x) + (a2.x + a3.x);
        acc.y += (a0.y + a1.y) + (a2.y + a3.y);
        acc.z += (a0.z + a1.z) + (a2.z + a3.z);
        acc.w += (a0.w + a1.w) + (a2.w + a3.w);
    }
    for (; e < end; ++e) {
        float4 a0 = *(const float4*)&base[(size_t)csr[e] * 32];
        acc.x += a0.x; acc.y += a0.y; acc.z += a0.z; acc.w += a0.w;
    }
    float di = dinv[v];
    float4* op = (float4*)(out + (size_t)v * 32 + 4 * lc);
    float4 o = *op;
    o.x += di * acc.x; o.y += di * acc.y; o.z += di * acc.z; o.w += di * acc.w;
    *op = o;
}

// ---------------- launch ----------------

extern "C" void kernel_launch(void* const* d_in, const int* in_sizes, int n_in,
                              void* d_out, int out_size, void* d_ws, size_t ws_size,
                              hipStream_t stream) {
    const float* x    = (const float*)d_in[0];
    const int*   ei   = (const int*)d_in[1];
    const float* W_in = (const float*)d_in[2];
    const float* b_in = (const float*)d_in[3];
    const float* Wg   = (const float*)d_in[4];  // [3][64][64]
    const float* bg   = (const float*)d_in[5];  // [3][64]
    const float* Ws   = (const float*)d_in[6];  // [3][64][32]
    const float* bs   = (const float*)d_in[7];  // [3][32]
    const float* Wl   = (const float*)d_in[8];  // [64][32]
    const float* bl   = (const float*)d_in[9];  // [32]

    const int N = in_sizes[0] / 128;
    const int E = in_sizes[1] / 2;
    const int NB = cdiv(N, 1 << BSH);
    const int* srcp = ei;
    const int* dstp = ei + E;

    char* p = (char*)d_ws;
    float*    hwA      = (float*)p;    p += (size_t)N * HID * 4;
    float*    hwB      = (float*)p;    p += (size_t)N * HID * 4;
    unsigned* bbuf     = (unsigned*)p; p += (size_t)NB * BCAP * 4;
    int*      csr      = (int*)p;      p += (size_t)E * 4;
    int*      rowstart = (int*)p;      p += ((size_t)N + 1) * 4;
    float*    dinv     = (float*)p;    p += (size_t)N * 4;
    int*      bcur     = (int*)p;      p += (size_t)NB * 4;
    int*      bstart   = (int*)p;      p += (size_t)NB * 4;
    float*    out      = (float*)d_out;

    const int B = 256;

    zero_kernel<<<cdiv(NB, B), B, 0, stream>>>(bcur, NB);
    bucket_fill_kernel<<<cdiv(E, B), B, 0, stream>>>(srcp, dstp, bcur, bbuf, E);
    bscan_kernel<<<1, 1024, 0, stream>>>(bcur, bstart, NB);
    build_csr_kernel<<<NB, 128, 0, stream>>>(bcur, bstart, bbuf, csr, rowstart, dinv, N, E);

    input_fused_kernel<<<cdiv(N, 64), B, 0, stream>>>(
        x, W_in, b_in, Wg, Ws, dinv, bl, bs, hwA, out, N);

    gather_transform_kernel<false><<<cdiv(N, 64), B, 0, stream>>>(
        rowstart, csr, dinv, hwA, bg, Wg + 4096, Ws + 2048, hwB, out, N);

    gather_transform_kernel<false><<<cdiv(N, 64), B, 0, stream>>>(
        rowstart, csr, dinv, hwB, bg + 64, Wg + 8192, Ws + 4096, hwA, out, N);

    gather_transform_kernel<true><<<cdiv(N, 64), B, 0, stream>>>(
        rowstart, csr, dinv, hwA, bg + 128, nullptr, Wl, hwB, nullptr, N);

    gather_out_kernel<<<cdiv(N, 32), B, 0, stream>>>(rowstart, csr, dinv, hwB, out, N);
}

// Round 9
// 513.277 us; speedup vs baseline: 1.2708x; 1.2708x over previous
//
#include <hip/hip_runtime.h>

// GCN encoder, fused gather formulation + radix-partition CSR build.
// Measured models (MI355X):
//  - same-address atomic chain ~184ns/op (r3).
//  - cross-XCD line sharing on scatter/append => zero write-combining:
//    WRITE_SIZE = E*64B (r2 fill 105MB, r7 bucket_fill 100MB). Fix: per-WG
//    exclusive output runs (radix partition, no global atomics).
//  - 1-output/thread dense = latency-stalled (r5) -> 4x4 register tiling.
//  - big LDS kills occupancy (r6: 50.7KB -> occ 26%) -> no x staging.
// Pipeline (10 dispatches):
//   hist | colscan | bscan | partition | build_csr
//   K0 : h0=x@Win+b -> {out = allbias + h0@Ws0, hwA=(h0@Wg0)*dinv}
//   GT1: gather(hwA)->h1 -> {out+=h1@Ws1, hwB=(h1@Wg1)*dinv}
//   GT2: gather(hwB)->h2 -> {out+=h2@Ws2, hwA=(h2@Wg2)*dinv}
//   GT3: gather(hwA)->h3 -> hwB32=(h3@Wl)*dinv
//   GO : out += dinv * gather32(hwB32)
// Identity: gcn(h)[v] = dinv[v] * sum_{s in nbr(v) u {v}} (hW*dinv)[s] + b

#define HID 64
#define LAT 32
#define PW 128         // partition WGs (chunks); per-(WG,bin) run ~16 edges = 64B

static inline int cdiv(long long a, long long b) { return (int)((a + b - 1) / b); }

// ---------------- CSR build: radix partition by dst>>7 ----------------

// hist[bin*PW + w] = #edges in WG w's chunk with dst>>7 == bin
__global__ __launch_bounds__(256) void hist_kernel(const int* __restrict__ dst,
                                                   int* __restrict__ hist,
                                                   int E, int nb1, int chunk) {
    __shared__ int h[1024];
    int w = blockIdx.x, t = threadIdx.x;
    for (int i = t; i < nb1; i += 256) h[i] = 0;
    __syncthreads();
    int beg = w * chunk, end = min(E, beg + chunk);
    for (int e = beg + t; e < end; e += 256) atomicAdd(&h[dst[e] >> 7], 1);
    __syncthreads();
    for (int i = t; i < nb1; i += 256) hist[i * PW + w] = h[i];
}

// per-bin exclusive prefix over WGs + bin total
__global__ __launch_bounds__(PW) void colscan_kernel(const int* __restrict__ hist,
                                                     int* __restrict__ colprefix,
                                                     int* __restrict__ btot) {
    __shared__ int s[PW];
    int b = blockIdx.x, t = threadIdx.x;
    int v = hist[b * PW + t];
    s[t] = v;
    __syncthreads();
    for (int off = 1; off < PW; off <<= 1) {
        int x = (t >= off) ? s[t - off] : 0;
        __syncthreads();
        s[t] += x;
        __syncthreads();
    }
    colprefix[b * PW + t] = s[t] - v;
    if (t == PW - 1) btot[b] = s[t];
}

// exclusive scan of bin totals (nb1 <= 1024)
__global__ __launch_bounds__(1024) void bscan_kernel(const int* __restrict__ btot,
                                                     int* __restrict__ bstart, int nb1, int E) {
    __shared__ int s[1024];
    int t = threadIdx.x;
    int v = (t < nb1) ? btot[t] : 0;
    s[t] = v;
    __syncthreads();
    for (int off = 1; off < 1024; off <<= 1) {
        int x = (t >= off) ? s[t - off] : 0;
        __syncthreads();
        s[t] += x;
        __syncthreads();
    }
    if (t < nb1) bstart[t] = s[t] - v;
    if (t == 0) bstart[nb1] = E;
}

// scatter packed records; each (WG,bin) output run is contiguous & exclusive
__global__ __launch_bounds__(256) void partition_kernel(
        const int* __restrict__ src, const int* __restrict__ dst,
        const int* __restrict__ bstart, const int* __restrict__ colprefix,
        unsigned* __restrict__ bbuf, int E, int nb1, int chunk) {
    __shared__ int cur[1024];
    int w = blockIdx.x, t = threadIdx.x;
    for (int i = t; i < nb1; i += 256) cur[i] = bstart[i] + colprefix[i * PW + w];
    __syncthreads();
    int beg = w * chunk, end = min(E, beg + chunk);
    for (int e = beg + t; e < end; e += 256) {
        int s = src[e], d = dst[e];
        int pos = atomicAdd(&cur[d >> 7], 1);   // LDS atomic, ~16/addr
        bbuf[pos] = ((unsigned)(d & 127) << 17) | (unsigned)s;
    }
}

// per-bucket (128 nodes): LDS count -> scan -> clustered csr fill;
// emits rowstart[v], dinv[v]. bbuf region is dense & contiguous (L2-hot).
__global__ __launch_bounds__(256) void build_csr_kernel(
        const int* __restrict__ bstart, const unsigned* __restrict__ bbuf,
        int* __restrict__ csr, int* __restrict__ rowstart, float* __restrict__ dinv,
        int n, int E) {
    __shared__ int lcount[128], lpre[128], lcur[128];
    int b = blockIdx.x, t = threadIdx.x;
    int bst = bstart[b], bend = bstart[b + 1];

    if (t < 128) lcount[t] = 0;
    __syncthreads();
    for (int i = bst + t; i < bend; i += 256) atomicAdd(&lcount[bbuf[i] >> 17], 1);
    __syncthreads();
    if (t == 0) {
        int run = 0;
        for (int k = 0; k < 128; ++k) {
            lpre[k] = run;
            lcur[k] = run;
            run += lcount[k];
        }
    }
    __syncthreads();
    if (t < 128) {
        int v = (b << 7) + t;
        if (v < n) {
            rowstart[v] = bst + lpre[t];
            dinv[v] = rsqrtf((float)(lcount[t] + 1));
        }
    }
    if (b == 0 && t == 0) rowstart[n] = E;
    for (int i = bst + t; i < bend; i += 256) {
        unsigned p = bbuf[i];
        int pos = bst + atomicAdd(&lcur[p >> 17], 1);
        csr[pos] = (int)(p & 0x1FFFFu);
    }
}

// ---------------- K0: input layer, fused, 4x4 tiled, no x staging ----------------

__global__ __launch_bounds__(256) void input_fused_kernel(
        const float* __restrict__ x, const float* __restrict__ Win,
        const float* __restrict__ bin, const float* __restrict__ Wg0,
        const float* __restrict__ Ws0, const float* __restrict__ dinv,
        const float* __restrict__ bl, const float* __restrict__ bs,
        float* __restrict__ hw, float* __restrict__ out, int n) {
    __shared__ float h0[64 * 68];   // stride 68: 2-way bank alias (free), 16B rows
    int t = threadIdx.x;
    int vbase = blockIdx.x * 64;
    int rg = t >> 4, lc = t & 15;

    int r0 = vbase + rg * 4;
    const float* xp0 = x + (size_t)(r0 + 0 < n ? r0 + 0 : n - 1) * 128;
    const float* xp1 = x + (size_t)(r0 + 1 < n ? r0 + 1 : n - 1) * 128;
    const float* xp2 = x + (size_t)(r0 + 2 < n ? r0 + 2 : n - 1) * 128;
    const float* xp3 = x + (size_t)(r0 + 3 < n ? r0 + 3 : n - 1) * 128;

    {
        float4 b4 = *(const float4*)&bin[4 * lc];
        float4 a0 = b4, a1 = b4, a2 = b4, a3 = b4;
#pragma unroll 4
        for (int k = 0; k < 128; k += 4) {
            float4 x0 = *(const float4*)&xp0[k];
            float4 x1 = *(const float4*)&xp1[k];
            float4 x2 = *(const float4*)&xp2[k];
            float4 x3 = *(const float4*)&xp3[k];
            float4 w;
            w = *(const float4*)&Win[(k + 0) * 64 + 4 * lc];
            a0.x = fmaf(x0.x, w.x, a0.x); a0.y = fmaf(x0.x, w.y, a0.y);
            a0.z = fmaf(x0.x, w.z, a0.z); a0.w = fmaf(x0.x, w.w, a0.w);
            a1.x = fmaf(x1.x, w.x, a1.x); a1.y = fmaf(x1.x, w.y, a1.y);
            a1.z = fmaf(x1.x, w.z, a1.z); a1.w = fmaf(x1.x, w.w, a1.w);
            a2.x = fmaf(x2.x, w.x, a2.x); a2.y = fmaf(x2.x, w.y, a2.y);
            a2.z = fmaf(x2.x, w.z, a2.z); a2.w = fmaf(x2.x, w.w, a2.w);
            a3.x = fmaf(x3.x, w.x, a3.x); a3.y = fmaf(x3.x, w.y, a3.y);
            a3.z = fmaf(x3.x, w.z, a3.z); a3.w = fmaf(x3.x, w.w, a3.w);
            w = *(const float4*)&Win[(k + 1) * 64 + 4 * lc];
            a0.x = fmaf(x0.y, w.x, a0.x); a0.y = fmaf(x0.y, w.y, a0.y);
            a0.z = fmaf(x0.y, w.z, a0.z); a0.w = fmaf(x0.y, w.w, a0.w);
            a1.x = fmaf(x1.y, w.x, a1.x); a1.y = fmaf(x1.y, w.y, a1.y);
            a1.z = fmaf(x1.y, w.z, a1.z); a1.w = fmaf(x1.y, w.w, a1.w);
            a2.x = fmaf(x2.y, w.x, a2.x); a2.y = fmaf(x2.y, w.y, a2.y);
            a2.z = fmaf(x2.y, w.z, a2.z); a2.w = fmaf(x2.y, w.w, a2.w);
            a3.x = fmaf(x3.y, w.x, a3.x); a3.y = fmaf(x3.y, w.y, a3.y);
            a3.z = fmaf(x3.y, w.z, a3.z); a3.w = fmaf(x3.y, w.w, a3.w);
            w = *(const float4*)&Win[(k + 2) * 64 + 4 * lc];
            a0.x = fmaf(x0.z, w.x, a0.x); a0.y = fmaf(x0.z, w.y, a0.y);
            a0.z = fmaf(x0.z, w.z, a0.z); a0.w = fmaf(x0.z, w.w, a0.w);
            a1.x = fmaf(x1.z, w.x, a1.x); a1.y = fmaf(x1.z, w.y, a1.y);
            a1.z = fmaf(x1.z, w.z, a1.z); a1.w = fmaf(x1.z, w.w, a1.w);
            a2.x = fmaf(x2.z, w.x, a2.x); a2.y = fmaf(x2.z, w.y, a2.y);
            a2.z = fmaf(x2.z, w.z, a2.z); a2.w = fmaf(x2.z, w.w, a2.w);
            a3.x = fmaf(x3.z, w.x, a3.x); a3.y = fmaf(x3.z, w.y, a3.y);
            a3.z = fmaf(x3.z, w.z, a3.z); a3.w = fmaf(x3.z, w.w, a3.w);
            w = *(const float4*)&Win[(k + 3) * 64 + 4 * lc];
            a0.x = fmaf(x0.w, w.x, a0.x); a0.y = fmaf(x0.w, w.y, a0.y);
            a0.z = fmaf(x0.w, w.z, a0.z); a0.w = fmaf(x0.w, w.w, a0.w);
            a1.x = fmaf(x1.w, w.x, a1.x); a1.y = fmaf(x1.w, w.y, a1.y);
            a1.z = fmaf(x1.w, w.z, a1.z); a1.w = fmaf(x1.w, w.w, a1.w);
            a2.x = fmaf(x2.w, w.x, a2.x); a2.y = fmaf(x2.w, w.y, a2.y);
            a2.z = fmaf(x2.w, w.z, a2.z); a2.w = fmaf(x2.w, w.w, a2.w);
            a3.x = fmaf(x3.w, w.x, a3.x); a3.y = fmaf(x3.w, w.y, a3.y);
            a3.z = fmaf(x3.w, w.z, a3.z); a3.w = fmaf(x3.w, w.w, a3.w);
        }
        *(float4*)&h0[(rg * 4 + 0) * 68 + 4 * lc] = a0;
        *(float4*)&h0[(rg * 4 + 1) * 68 + 4 * lc] = a1;
        *(float4*)&h0[(rg * 4 + 2) * 68 + 4 * lc] = a2;
        *(float4*)&h0[(rg * 4 + 3) * 68 + 4 * lc] = a3;
    }
    __syncthreads();

    // Phase2a: hw = (h0 @ Wg0) * dinv
    {
        float4 a0, a1, a2, a3;
        a0 = a1 = a2 = a3 = make_float4(0.f, 0.f, 0.f, 0.f);
#pragma unroll 8
        for (int k = 0; k < 64; ++k) {
            float4 w = *(const float4*)&Wg0[k * 64 + 4 * lc];
            float x0 = h0[(rg * 4 + 0) * 68 + k];
            float x1 = h0[(rg * 4 + 1) * 68 + k];
            float x2 = h0[(rg * 4 + 2) * 68 + k];
            float x3 = h0[(rg * 4 + 3) * 68 + k];
            a0.x = fmaf(x0, w.x, a0.x); a0.y = fmaf(x0, w.y, a0.y);
            a0.z = fmaf(x0, w.z, a0.z); a0.w = fmaf(x0, w.w, a0.w);
            a1.x = fmaf(x1, w.x, a1.x); a1.y = fmaf(x1, w.y, a1.y);
            a1.z = fmaf(x1, w.z, a1.z); a1.w = fmaf(x1, w.w, a1.w);
            a2.x = fmaf(x2, w.x, a2.x); a2.y = fmaf(x2, w.y, a2.y);
            a2.z = fmaf(x2, w.z, a2.z); a2.w = fmaf(x2, w.w, a2.w);
            a3.x = fmaf(x3, w.x, a3.x); a3.y = fmaf(x3, w.y, a3.y);
            a3.z = fmaf(x3, w.z, a3.z); a3.w = fmaf(x3, w.w, a3.w);
        }
#pragma unroll
        for (int r = 0; r < 4; ++r) {
            int v = vbase + rg * 4 + r;
            if (v < n) {
                float di = dinv[v];
                float4 a = (r == 0) ? a0 : (r == 1) ? a1 : (r == 2) ? a2 : a3;
                a.x *= di; a.y *= di; a.z *= di; a.w *= di;
                *(float4*)&hw[(size_t)v * 64 + 4 * lc] = a;
            }
        }
    }

    // Phase2b: out = (bl + sum bs) + h0 @ Ws0   (store, no RMW)
    {
        int sg = t >> 3, sc = t & 7;
        float4 bb = *(const float4*)&bl[4 * sc];
        float4 q0 = *(const float4*)&bs[4 * sc];
        float4 q1 = *(const float4*)&bs[LAT + 4 * sc];
        float4 q2 = *(const float4*)&bs[2 * LAT + 4 * sc];
        bb.x += q0.x + q1.x + q2.x; bb.y += q0.y + q1.y + q2.y;
        bb.z += q0.z + q1.z + q2.z; bb.w += q0.w + q1.w + q2.w;
        float4 a0 = bb, a1 = bb;
#pragma unroll 8
        for (int k = 0; k < 64; ++k) {
            float4 w = *(const float4*)&Ws0[k * 32 + 4 * sc];
            float x0 = h0[(sg * 2 + 0) * 68 + k];
            float x1 = h0[(sg * 2 + 1) * 68 + k];
            a0.x = fmaf(x0, w.x, a0.x); a0.y = fmaf(x0, w.y, a0.y);
            a0.z = fmaf(x0, w.z, a0.z); a0.w = fmaf(x0, w.w, a0.w);
            a1.x = fmaf(x1, w.x, a1.x); a1.y = fmaf(x1, w.y, a1.y);
            a1.z = fmaf(x1, w.z, a1.z); a1.w = fmaf(x1, w.w, a1.w);
        }
#pragma unroll
        for (int r = 0; r < 2; ++r) {
            int v = vbase + sg * 2 + r;
            if (v < n)
                *(float4*)&out[(size_t)v * 32 + 4 * sc] = (r == 0) ? a0 : a1;
        }
    }
}

// ---------------- fused gather + transform, 64 nodes/block ----------------

template <bool LAST>
__global__ __launch_bounds__(256) void gather_transform_kernel(
        const int* __restrict__ rowstart, const int* __restrict__ csr,
        const float* __restrict__ dinv, const float* __restrict__ hwin,
        const float* __restrict__ bias, const float* __restrict__ Wg,
        const float* __restrict__ Ws, float* __restrict__ hwout,
        float* __restrict__ out, int n) {
    __shared__ float hL[64 * 68];
    int t = threadIdx.x;
    int vbase = blockIdx.x * 64;
    int ns = t >> 4, lc = t & 15;

    float4 b4 = *(const float4*)&bias[4 * lc];
#pragma unroll
    for (int b = 0; b < 4; ++b) {
        int row = b * 16 + ns;
        int v = vbase + row;
        if (v < n) {
            int beg = rowstart[v];
            int end = rowstart[v + 1];
            float di = dinv[v];
            float4 acc = *(const float4*)&hwin[(size_t)v * 64 + 4 * lc];  // self
            const float* base = hwin + 4 * lc;
            int e = beg;
            for (; e + 3 < end; e += 4) {
                int s0 = csr[e], s1 = csr[e + 1], s2 = csr[e + 2], s3 = csr[e + 3];
                float4 g0 = *(const float4*)&base[(size_t)s0 * 64];
                float4 g1 = *(const float4*)&base[(size_t)s1 * 64];
                float4 g2 = *(const float4*)&base[(size_t)s2 * 64];
                float4 g3 = *(const float4*)&base[(size_t)s3 * 64];
                acc.x += (g0.x + g1.x) + (g2.x + g3.x);
                acc.y += (g0.y + g1.y) + (g2.y + g3.y);
                acc.z += (g0.z + g1.z) + (g2.z + g3.z);
                acc.w += (g0.w + g1.w) + (g2.w + g3.w);
            }
            for (; e < end; ++e) {
                float4 g0 = *(const float4*)&base[(size_t)csr[e] * 64];
                acc.x += g0.x; acc.y += g0.y; acc.z += g0.z; acc.w += g0.w;
            }
            float4 h;
            h.x = di * acc.x + b4.x; h.x = h.x > 0.f ? h.x : 0.2f * h.x;
            h.y = di * acc.y + b4.y; h.y = h.y > 0.f ? h.y : 0.2f * h.y;
            h.z = di * acc.z + b4.z; h.z = h.z > 0.f ? h.z : 0.2f * h.z;
            h.w = di * acc.w + b4.w; h.w = h.w > 0.f ? h.w : 0.2f * h.w;
            *(float4*)&hL[row * 68 + 4 * lc] = h;
        }
    }
    __syncthreads();

    if (!LAST) {
        int rg = t >> 4;
        float4 a0, a1, a2, a3;
        a0 = a1 = a2 = a3 = make_float4(0.f, 0.f, 0.f, 0.f);
#pragma unroll 8
        for (int k = 0; k < 64; ++k) {
            float4 w = *(const float4*)&Wg[k * 64 + 4 * lc];
            float x0 = hL[(rg * 4 + 0) * 68 + k];
            float x1 = hL[(rg * 4 + 1) * 68 + k];
            float x2 = hL[(rg * 4 + 2) * 68 + k];
            float x3 = hL[(rg * 4 + 3) * 68 + k];
            a0.x = fmaf(x0, w.x, a0.x); a0.y = fmaf(x0, w.y, a0.y);
            a0.z = fmaf(x0, w.z, a0.z); a0.w = fmaf(x0, w.w, a0.w);
            a1.x = fmaf(x1, w.x, a1.x); a1.y = fmaf(x1, w.y, a1.y);
            a1.z = fmaf(x1, w.z, a1.z); a1.w = fmaf(x1, w.w, a1.w);
            a2.x = fmaf(x2, w.x, a2.x); a2.y = fmaf(x2, w.y, a2.y);
            a2.z = fmaf(x2, w.z, a2.z); a2.w = fmaf(x2, w.w, a2.w);
            a3.x = fmaf(x3, w.x, a3.x); a3.y = fmaf(x3, w.y, a3.y);
            a3.z = fmaf(x3, w.z, a3.z); a3.w = fmaf(x3, w.w, a3.w);
        }
#pragma unroll
        for (int r = 0; r < 4; ++r) {
            int v = vbase + rg * 4 + r;
            if (v < n) {
                float di = dinv[v];
                float4 a = (r == 0) ? a0 : (r == 1) ? a1 : (r == 2) ? a2 : a3;
                a.x *= di; a.y *= di; a.z *= di; a.w *= di;
                *(float4*)&hwout[(size_t)v * 64 + 4 * lc] = a;
            }
        }

        int sg = t >> 3, sc = t & 7;
        float4 s0, s1;
        s0 = s1 = make_float4(0.f, 0.f, 0.f, 0.f);
#pragma unroll 8
        for (int k = 0; k < 64; ++k) {
            float4 w = *(const float4*)&Ws[k * 32 + 4 * sc];
            float x0 = hL[(sg * 2 + 0) * 68 + k];
            float x1 = hL[(sg * 2 + 1) * 68 + k];
            s0.x = fmaf(x0, w.x, s0.x); s0.y = fmaf(x0, w.y, s0.y);
            s0.z = fmaf(x0, w.z, s0.z); s0.w = fmaf(x0, w.w, s0.w);
            s1.x = fmaf(x1, w.x, s1.x); s1.y = fmaf(x1, w.y, s1.y);
            s1.z = fmaf(x1, w.z, s1.z); s1.w = fmaf(x1, w.w, s1.w);
        }
#pragma unroll
        for (int r = 0; r < 2; ++r) {
            int v = vbase + sg * 2 + r;
            if (v < n) {
                float4 a = (r == 0) ? s0 : s1;
                float4* op = (float4*)(out + (size_t)v * 32 + 4 * sc);
                float4 o = *op;
                o.x += a.x; o.y += a.y; o.z += a.z; o.w += a.w;
                *op = o;
            }
        }
    } else {
        int sg = t >> 3, sc = t & 7;
        float4 s0, s1;
        s0 = s1 = make_float4(0.f, 0.f, 0.f, 0.f);
#pragma unroll 8
        for (int k = 0; k < 64; ++k) {
            float4 w = *(const float4*)&Ws[k * 32 + 4 * sc];  // Ws == Wl
            float x0 = hL[(sg * 2 + 0) * 68 + k];
            float x1 = hL[(sg * 2 + 1) * 68 + k];
            s0.x = fmaf(x0, w.x, s0.x); s0.y = fmaf(x0, w.y, s0.y);
            s0.z = fmaf(x0, w.z, s0.z); s0.w = fmaf(x0, w.w, s0.w);
            s1.x = fmaf(x1, w.x, s1.x); s1.y = fmaf(x1, w.y, s1.y);
            s1.z = fmaf(x1, w.z, s1.z); s1.w = fmaf(x1, w.w, s1.w);
        }
#pragma unroll
        for (int r = 0; r < 2; ++r) {
            int v = vbase + sg * 2 + r;
            if (v < n) {
                float di = dinv[v];
                float4 a = (r == 0) ? s0 : s1;
                a.x *= di; a.y *= di; a.z *= di; a.w *= di;
                *(float4*)&hwout[(size_t)v * 32 + 4 * sc] = a;
            }
        }
    }
}

// ---------------- final gather into output (32 ch, 8 lanes/node) ----------------

__global__ __launch_bounds__(256) void gather_out_kernel(
        const int* __restrict__ rowstart, const int* __restrict__ csr,
        const float* __restrict__ dinv, const float* __restrict__ hwl,
        float* __restrict__ out, int n) {
    int t = threadIdx.x;
    int lr = t >> 3, lc = t & 7;
    int v = blockIdx.x * 32 + lr;
    if (v >= n) return;
    int beg = rowstart[v], end = rowstart[v + 1];
    float4 acc = *(const float4*)&hwl[(size_t)v * 32 + 4 * lc];
    const float* base = hwl + 4 * lc;
    int e = beg;
    for (; e + 3 < end; e += 4) {
        int s0 = csr[e], s1 = csr[e + 1], s2 = csr[e + 2], s3 = csr[e + 3];
        float4 a0 = *(const float4*)&base[(size_t)s0 * 32];
        float4 a1 = *(const float4*)&base[(size_t)s1 * 32];
        float4 a2 = *(const float4*)&base[(size_t)s2 * 32];
        float4 a3 = *(const float4*)&base[(size_t)s3 * 32];
        acc.x += (a0.x + a1.x) + (a2.x + a3.x);
        acc.y += (a0.y + a1.y) + (a2.y + a3.y);
        acc.z += (a0.z + a1.z) + (a2.z + a3.z);
        acc.w += (a0.w + a1.w) + (a2.w + a3.w);
    }
    for (; e < end; ++e) {
        float4 a0 = *(const float4*)&base[(size_t)csr[e] * 32];
        acc.x += a0.x; acc.y += a0.y; acc.z += a0.z; acc.w += a0.w;
    }
    float di = dinv[v];
    float4* op = (float4*)(out + (size_t)v * 32 + 4 * lc);
    float4 o = *op;
    o.x += di * acc.x; o.y += di * acc.y; o.z += di * acc.z; o.w += di * acc.w;
    *op = o;
}

// ---------------- launch ----------------

extern "C" void kernel_launch(void* const* d_in, const int* in_sizes, int n_in,
                              void* d_out, int out_size, void* d_ws, size_t ws_size,
                              hipStream_t stream) {
    const float* x    = (const float*)d_in[0];
    const int*   ei   = (const int*)d_in[1];
    const float* W_in = (const float*)d_in[2];
    const float* b_in = (const float*)d_in[3];
    const float* Wg   = (const float*)d_in[4];  // [3][64][64]
    const float* bg   = (const float*)d_in[5];  // [3][64]
    const float* Ws   = (const float*)d_in[6];  // [3][64][32]
    const float* bs   = (const float*)d_in[7];  // [3][32]
    const float* Wl   = (const float*)d_in[8];  // [64][32]
    const float* bl   = (const float*)d_in[9];  // [32]

    const int N = in_sizes[0] / 128;
    const int E = in_sizes[1] / 2;
    const int nb1 = cdiv(N, 128);          // coarse buckets (dst>>7)
    const int chunk = cdiv(E, PW);
    const int* srcp = ei;
    const int* dstp = ei + E;

    char* p = (char*)d_ws;
    float*    hwA      = (float*)p;    p += (size_t)N * HID * 4;
    float*    hwB      = (float*)p;    p += (size_t)N * HID * 4;
    unsigned* bbuf     = (unsigned*)p; p += (size_t)E * 4;
    int*      csr      = (int*)p;      p += (size_t)E * 4;
    int*      rowstart = (int*)p;      p += ((size_t)N + 1) * 4;
    float*    dinv     = (float*)p;    p += (size_t)N * 4;
    int*      hist     = (int*)p;      p += (size_t)nb1 * PW * 4;
    int*      colpre   = (int*)p;      p += (size_t)nb1 * PW * 4;
    int*      btot     = (int*)p;      p += (size_t)nb1 * 4;
    int*      bstart   = (int*)p;      p += ((size_t)nb1 + 1) * 4;
    float*    out      = (float*)d_out;

    const int B = 256;

    // CSR build: radix partition (no global atomics)
    hist_kernel<<<PW, B, 0, stream>>>(dstp, hist, E, nb1, chunk);
    colscan_kernel<<<nb1, PW, 0, stream>>>(hist, colpre, btot);
    bscan_kernel<<<1, 1024, 0, stream>>>(btot, bstart, nb1, E);
    partition_kernel<<<PW, B, 0, stream>>>(srcp, dstp, bstart, colpre, bbuf, E, nb1, chunk);
    build_csr_kernel<<<nb1, B, 0, stream>>>(bstart, bbuf, csr, rowstart, dinv, N, E);

    input_fused_kernel<<<cdiv(N, 64), B, 0, stream>>>(
        x, W_in, b_in, Wg, Ws, dinv, bl, bs, hwA, out, N);

    gather_transform_kernel<false><<<cdiv(N, 64), B, 0, stream>>>(
        rowstart, csr, dinv, hwA, bg, Wg + 4096, Ws + 2048, hwB, out, N);

    gather_transform_kernel<false><<<cdiv(N, 64), B, 0, stream>>>(
        rowstart, csr, dinv, hwB, bg + 64, Wg + 8192, Ws + 4096, hwA, out, N);

    gather_transform_kernel<true><<<cdiv(N, 64), B, 0, stream>>>(
        rowstart, csr, dinv, hwA, bg + 128, nullptr, Wl, hwB, nullptr, N);

    gather_out_kernel<<<cdiv(N, 32), B, 0, stream>>>(rowstart, csr, dinv, hwB, out, N);
}

// Round 11
// 495.863 us; speedup vs baseline: 1.3154x; 1.0351x over previous
//
#include <hip/hip_runtime.h>

// GCN encoder, fused gather formulation + radix-partition CSR build.
// Measured models (MI355X):
//  - same-address atomic chain ~184ns/op (r3).
//  - cross-XCD line sharing on scatter/append => zero write-combining (r2/r7:
//    WRITE = E*64B). Fix: radix partition, per-WG exclusive output runs (r9 ok).
//  - 1-output/thread dense = latency-stalled (r5) -> 4x4 register tiling.
//  - big LDS kills occupancy (r6) -> no x staging.
//  - gathers latency-bound (r9: VALUBusy ~23%, HBM ~8%) -> constant-8
//    outstanding row loads: 8-unrolled main loop + ONE masked 8-wide tail.
// Pipeline (10 dispatches):
//   hist | colscan | bscan | partition | build_csr
//   K0 : h0=x@Win+b -> {out = allbias + h0@Ws0, hwA=(h0@Wg0)*dinv}
//   GT1: gather(hwA)->h1 -> {out+=h1@Ws1, hwB=(h1@Wg1)*dinv}
//   GT2: gather(hwB)->h2 -> {out+=h2@Ws2, hwA=(h2@Wg2)*dinv}
//   GT3: gather(hwA)->h3 -> hwB32=(h3@Wl)*dinv
//   GO : out += dinv * gather32(hwB32)
// Identity: gcn(h)[v] = dinv[v] * sum_{s in nbr(v) u {v}} (hW*dinv)[s] + b

#define HID 64
#define LAT 32
#define PW 128         // partition WGs

static inline int cdiv(long long a, long long b) { return (int)((a + b - 1) / b); }

// ---------------- CSR build: radix partition by dst>>7 ----------------

__global__ __launch_bounds__(256) void hist_kernel(const int* __restrict__ dst,
                                                   int* __restrict__ hist,
                                                   int E, int nb1, int chunk) {
    __shared__ int h[1024];
    int w = blockIdx.x, t = threadIdx.x;
    for (int i = t; i < nb1; i += 256) h[i] = 0;
    __syncthreads();
    int beg = w * chunk, end = min(E, beg + chunk);
    for (int e = beg + t; e < end; e += 256) atomicAdd(&h[dst[e] >> 7], 1);
    __syncthreads();
    for (int i = t; i < nb1; i += 256) hist[i * PW + w] = h[i];
}

__global__ __launch_bounds__(PW) void colscan_kernel(const int* __restrict__ hist,
                                                     int* __restrict__ colprefix,
                                                     int* __restrict__ btot) {
    __shared__ int s[PW];
    int b = blockIdx.x, t = threadIdx.x;
    int v = hist[b * PW + t];
    s[t] = v;
    __syncthreads();
    for (int off = 1; off < PW; off <<= 1) {
        int x = (t >= off) ? s[t - off] : 0;
        __syncthreads();
        s[t] += x;
        __syncthreads();
    }
    colprefix[b * PW + t] = s[t] - v;
    if (t == PW - 1) btot[b] = s[t];
}

__global__ __launch_bounds__(1024) void bscan_kernel(const int* __restrict__ btot,
                                                     int* __restrict__ bstart, int nb1, int E) {
    __shared__ int s[1024];
    int t = threadIdx.x;
    int v = (t < nb1) ? btot[t] : 0;
    s[t] = v;
    __syncthreads();
    for (int off = 1; off < 1024; off <<= 1) {
        int x = (t >= off) ? s[t - off] : 0;
        __syncthreads();
        s[t] += x;
        __syncthreads();
    }
    if (t < nb1) bstart[t] = s[t] - v;
    if (t == 0) bstart[nb1] = E;
}

__global__ __launch_bounds__(256) void partition_kernel(
        const int* __restrict__ src, const int* __restrict__ dst,
        const int* __restrict__ bstart, const int* __restrict__ colprefix,
        unsigned* __restrict__ bbuf, int E, int nb1, int chunk) {
    __shared__ int cur[1024];
    int w = blockIdx.x, t = threadIdx.x;
    for (int i = t; i < nb1; i += 256) cur[i] = bstart[i] + colprefix[i * PW + w];
    __syncthreads();
    int beg = w * chunk, end = min(E, beg + chunk);
    for (int e = beg + t; e < end; e += 256) {
        int s = src[e], d = dst[e];
        int pos = atomicAdd(&cur[d >> 7], 1);
        bbuf[pos] = ((unsigned)(d & 127) << 17) | (unsigned)s;
    }
}

__global__ __launch_bounds__(256) void build_csr_kernel(
        const int* __restrict__ bstart, const unsigned* __restrict__ bbuf,
        int* __restrict__ csr, int* __restrict__ rowstart, float* __restrict__ dinv,
        int n, int E) {
    __shared__ int lcount[128], lpre[128], lcur[128];
    int b = blockIdx.x, t = threadIdx.x;
    int bst = bstart[b], bend = bstart[b + 1];

    if (t < 128) lcount[t] = 0;
    __syncthreads();
    for (int i = bst + t; i < bend; i += 256) atomicAdd(&lcount[bbuf[i] >> 17], 1);
    __syncthreads();
    if (t == 0) {
        int run = 0;
        for (int k = 0; k < 128; ++k) {
            lpre[k] = run;
            lcur[k] = run;
            run += lcount[k];
        }
    }
    __syncthreads();
    if (t < 128) {
        int v = (b << 7) + t;
        if (v < n) {
            rowstart[v] = bst + lpre[t];
            dinv[v] = rsqrtf((float)(lcount[t] + 1));
        }
    }
    if (b == 0 && t == 0) rowstart[n] = E;
    for (int i = bst + t; i < bend; i += 256) {
        unsigned p = bbuf[i];
        int pos = bst + atomicAdd(&lcur[p >> 17], 1);
        csr[pos] = (int)(p & 0x1FFFFu);
    }
}

// ---------------- K0: input layer, fused, 4x4 tiled, no x staging ----------------

__global__ __launch_bounds__(256) void input_fused_kernel(
        const float* __restrict__ x, const float* __restrict__ Win,
        const float* __restrict__ bin, const float* __restrict__ Wg0,
        const float* __restrict__ Ws0, const float* __restrict__ dinv,
        const float* __restrict__ bl, const float* __restrict__ bs,
        float* __restrict__ hw, float* __restrict__ out, int n) {
    __shared__ float h0[64 * 68];
    int t = threadIdx.x;
    int vbase = blockIdx.x * 64;
    int rg = t >> 4, lc = t & 15;

    int r0 = vbase + rg * 4;
    const float* xp0 = x + (size_t)(r0 + 0 < n ? r0 + 0 : n - 1) * 128;
    const float* xp1 = x + (size_t)(r0 + 1 < n ? r0 + 1 : n - 1) * 128;
    const float* xp2 = x + (size_t)(r0 + 2 < n ? r0 + 2 : n - 1) * 128;
    const float* xp3 = x + (size_t)(r0 + 3 < n ? r0 + 3 : n - 1) * 128;

    {
        float4 b4 = *(const float4*)&bin[4 * lc];
        float4 a0 = b4, a1 = b4, a2 = b4, a3 = b4;
#pragma unroll 4
        for (int k = 0; k < 128; k += 4) {
            float4 x0 = *(const float4*)&xp0[k];
            float4 x1 = *(const float4*)&xp1[k];
            float4 x2 = *(const float4*)&xp2[k];
            float4 x3 = *(const float4*)&xp3[k];
            float4 w;
            w = *(const float4*)&Win[(k + 0) * 64 + 4 * lc];
            a0.x = fmaf(x0.x, w.x, a0.x); a0.y = fmaf(x0.x, w.y, a0.y);
            a0.z = fmaf(x0.x, w.z, a0.z); a0.w = fmaf(x0.x, w.w, a0.w);
            a1.x = fmaf(x1.x, w.x, a1.x); a1.y = fmaf(x1.x, w.y, a1.y);
            a1.z = fmaf(x1.x, w.z, a1.z); a1.w = fmaf(x1.x, w.w, a1.w);
            a2.x = fmaf(x2.x, w.x, a2.x); a2.y = fmaf(x2.x, w.y, a2.y);
            a2.z = fmaf(x2.x, w.z, a2.z); a2.w = fmaf(x2.x, w.w, a2.w);
            a3.x = fmaf(x3.x, w.x, a3.x); a3.y = fmaf(x3.x, w.y, a3.y);
            a3.z = fmaf(x3.x, w.z, a3.z); a3.w = fmaf(x3.x, w.w, a3.w);
            w = *(const float4*)&Win[(k + 1) * 64 + 4 * lc];
            a0.x = fmaf(x0.y, w.x, a0.x); a0.y = fmaf(x0.y, w.y, a0.y);
            a0.z = fmaf(x0.y, w.z, a0.z); a0.w = fmaf(x0.y, w.w, a0.w);
            a1.x = fmaf(x1.y, w.x, a1.x); a1.y = fmaf(x1.y, w.y, a1.y);
            a1.z = fmaf(x1.y, w.z, a1.z); a1.w = fmaf(x1.y, w.w, a1.w);
            a2.x = fmaf(x2.y, w.x, a2.x); a2.y = fmaf(x2.y, w.y, a2.y);
            a2.z = fmaf(x2.y, w.z, a2.z); a2.w = fmaf(x2.y, w.w, a2.w);
            a3.x = fmaf(x3.y, w.x, a3.x); a3.y = fmaf(x3.y, w.y, a3.y);
            a3.z = fmaf(x3.y, w.z, a3.z); a3.w = fmaf(x3.y, w.w, a3.w);
            w = *(const float4*)&Win[(k + 2) * 64 + 4 * lc];
            a0.x = fmaf(x0.z, w.x, a0.x); a0.y = fmaf(x0.z, w.y, a0.y);
            a0.z = fmaf(x0.z, w.z, a0.z); a0.w = fmaf(x0.z, w.w, a0.w);
            a1.x = fmaf(x1.z, w.x, a1.x); a1.y = fmaf(x1.z, w.y, a1.y);
            a1.z = fmaf(x1.z, w.z, a1.z); a1.w = fmaf(x1.z, w.w, a1.w);
            a2.x = fmaf(x2.z, w.x, a2.x); a2.y = fmaf(x2.z, w.y, a2.y);
            a2.z = fmaf(x2.z, w.z, a2.z); a2.w = fmaf(x2.z, w.w, a2.w);
            a3.x = fmaf(x3.z, w.x, a3.x); a3.y = fmaf(x3.z, w.y, a3.y);
            a3.z = fmaf(x3.z, w.z, a3.z); a3.w = fmaf(x3.z, w.w, a3.w);
            w = *(const float4*)&Win[(k + 3) * 64 + 4 * lc];
            a0.x = fmaf(x0.w, w.x, a0.x); a0.y = fmaf(x0.w, w.y, a0.y);
            a0.z = fmaf(x0.w, w.z, a0.z); a0.w = fmaf(x0.w, w.w, a0.w);
            a1.x = fmaf(x1.w, w.x, a1.x); a1.y = fmaf(x1.w, w.y, a1.y);
            a1.z = fmaf(x1.w, w.z, a1.z); a1.w = fmaf(x1.w, w.w, a1.w);
            a2.x = fmaf(x2.w, w.x, a2.x); a2.y = fmaf(x2.w, w.y, a2.y);
            a2.z = fmaf(x2.w, w.z, a2.z); a2.w = fmaf(x2.w, w.w, a2.w);
            a3.x = fmaf(x3.w, w.x, a3.x); a3.y = fmaf(x3.w, w.y, a3.y);
            a3.z = fmaf(x3.w, w.z, a3.z); a3.w = fmaf(x3.w, w.w, a3.w);
        }
        *(float4*)&h0[(rg * 4 + 0) * 68 + 4 * lc] = a0;
        *(float4*)&h0[(rg * 4 + 1) * 68 + 4 * lc] = a1;
        *(float4*)&h0[(rg * 4 + 2) * 68 + 4 * lc] = a2;
        *(float4*)&h0[(rg * 4 + 3) * 68 + 4 * lc] = a3;
    }
    __syncthreads();

    // Phase2a: hw = (h0 @ Wg0) * dinv
    {
        float4 a0, a1, a2, a3;
        a0 = a1 = a2 = a3 = make_float4(0.f, 0.f, 0.f, 0.f);
#pragma unroll 8
        for (int k = 0; k < 64; ++k) {
            float4 w = *(const float4*)&Wg0[k * 64 + 4 * lc];
            float x0 = h0[(rg * 4 + 0) * 68 + k];
            float x1 = h0[(rg * 4 + 1) * 68 + k];
            float x2 = h0[(rg * 4 + 2) * 68 + k];
            float x3 = h0[(rg * 4 + 3) * 68 + k];
            a0.x = fmaf(x0, w.x, a0.x); a0.y = fmaf(x0, w.y, a0.y);
            a0.z = fmaf(x0, w.z, a0.z); a0.w = fmaf(x0, w.w, a0.w);
            a1.x = fmaf(x1, w.x, a1.x); a1.y = fmaf(x1, w.y, a1.y);
            a1.z = fmaf(x1, w.z, a1.z); a1.w = fmaf(x1, w.w, a1.w);
            a2.x = fmaf(x2, w.x, a2.x); a2.y = fmaf(x2, w.y, a2.y);
            a2.z = fmaf(x2, w.z, a2.z); a2.w = fmaf(x2, w.w, a2.w);
            a3.x = fmaf(x3, w.x, a3.x); a3.y = fmaf(x3, w.y, a3.y);
            a3.z = fmaf(x3, w.z, a3.z); a3.w = fmaf(x3, w.w, a3.w);
        }
#pragma unroll
        for (int r = 0; r < 4; ++r) {
            int v = vbase + rg * 4 + r;
            if (v < n) {
                float di = dinv[v];
                float4 a = (r == 0) ? a0 : (r == 1) ? a1 : (r == 2) ? a2 : a3;
                a.x *= di; a.y *= di; a.z *= di; a.w *= di;
                *(float4*)&hw[(size_t)v * 64 + 4 * lc] = a;
            }
        }
    }

    // Phase2b: out = (bl + sum bs) + h0 @ Ws0
    {
        int sg = t >> 3, sc = t & 7;
        float4 bb = *(const float4*)&bl[4 * sc];
        float4 q0 = *(const float4*)&bs[4 * sc];
        float4 q1 = *(const float4*)&bs[LAT + 4 * sc];
        float4 q2 = *(const float4*)&bs[2 * LAT + 4 * sc];
        bb.x += q0.x + q1.x + q2.x; bb.y += q0.y + q1.y + q2.y;
        bb.z += q0.z + q1.z + q2.z; bb.w += q0.w + q1.w + q2.w;
        float4 a0 = bb, a1 = bb;
#pragma unroll 8
        for (int k = 0; k < 64; ++k) {
            float4 w = *(const float4*)&Ws0[k * 32 + 4 * sc];
            float x0 = h0[(sg * 2 + 0) * 68 + k];
            float x1 = h0[(sg * 2 + 1) * 68 + k];
            a0.x = fmaf(x0, w.x, a0.x); a0.y = fmaf(x0, w.y, a0.y);
            a0.z = fmaf(x0, w.z, a0.z); a0.w = fmaf(x0, w.w, a0.w);
            a1.x = fmaf(x1, w.x, a1.x); a1.y = fmaf(x1, w.y, a1.y);
            a1.z = fmaf(x1, w.z, a1.z); a1.w = fmaf(x1, w.w, a1.w);
        }
#pragma unroll
        for (int r = 0; r < 2; ++r) {
            int v = vbase + sg * 2 + r;
            if (v < n)
                *(float4*)&out[(size_t)v * 32 + 4 * sc] = (r == 0) ? a0 : a1;
        }
    }
}

// ---------------- fused gather + transform, 64 nodes/block ----------------
// Gather: constant-8 outstanding row loads; ONE masked 8-wide tail pass.

template <bool LAST>
__global__ __launch_bounds__(256) void gather_transform_kernel(
        const int* __restrict__ rowstart, const int* __restrict__ csr,
        const float* __restrict__ dinv, const float* __restrict__ hwin,
        const float* __restrict__ bias, const float* __restrict__ Wg,
        const float* __restrict__ Ws, float* __restrict__ hwout,
        float* __restrict__ out, int n) {
    __shared__ float hL[64 * 68];
    int t = threadIdx.x;
    int vbase = blockIdx.x * 64;
    int ns = t >> 4, lc = t & 15;

    float4 b4 = *(const float4*)&bias[4 * lc];
#pragma unroll
    for (int b = 0; b < 4; ++b) {
        int row = b * 16 + ns;
        int v = vbase + row;
        if (v < n) {
            int beg = rowstart[v];
            int end = rowstart[v + 1];
            float di = dinv[v];
            float4 acc = *(const float4*)&hwin[(size_t)v * 64 + 4 * lc];  // self
            const float* base = hwin + 4 * lc;
            int e = beg;
            for (; e + 8 <= end; e += 8) {   // full 8-wide: no masks
                int s0 = csr[e + 0], s1 = csr[e + 1], s2 = csr[e + 2], s3 = csr[e + 3];
                int s4 = csr[e + 4], s5 = csr[e + 5], s6 = csr[e + 6], s7 = csr[e + 7];
                float4 g0 = *(const float4*)&base[(size_t)s0 * 64];
                float4 g1 = *(const float4*)&base[(size_t)s1 * 64];
                float4 g2 = *(const float4*)&base[(size_t)s2 * 64];
                float4 g3 = *(const float4*)&base[(size_t)s3 * 64];
                float4 g4 = *(const float4*)&base[(size_t)s4 * 64];
                float4 g5 = *(const float4*)&base[(size_t)s5 * 64];
                float4 g6 = *(const float4*)&base[(size_t)s6 * 64];
                float4 g7 = *(const float4*)&base[(size_t)s7 * 64];
                acc.x += ((g0.x + g1.x) + (g2.x + g3.x)) + ((g4.x + g5.x) + (g6.x + g7.x));
                acc.y += ((g0.y + g1.y) + (g2.y + g3.y)) + ((g4.y + g5.y) + (g6.y + g7.y));
                acc.z += ((g0.z + g1.z) + (g2.z + g3.z)) + ((g4.z + g5.z) + (g6.z + g7.z));
                acc.w += ((g0.w + g1.w) + (g2.w + g3.w)) + ((g4.w + g5.w) + (g6.w + g7.w));
            }
            if (e < end) {                    // ONE masked 8-wide tail
                int last = end - 1;
                int i1 = min(e + 1, last), i2 = min(e + 2, last), i3 = min(e + 3, last);
                int i4 = min(e + 4, last), i5 = min(e + 5, last), i6 = min(e + 6, last);
                float m1 = (e + 1 < end) ? 1.f : 0.f;
                float m2 = (e + 2 < end) ? 1.f : 0.f;
                float m3 = (e + 3 < end) ? 1.f : 0.f;
                float m4 = (e + 4 < end) ? 1.f : 0.f;
                float m5 = (e + 5 < end) ? 1.f : 0.f;
                float m6 = (e + 6 < end) ? 1.f : 0.f;
                int s0 = csr[e], s1 = csr[i1], s2 = csr[i2], s3 = csr[i3];
                int s4 = csr[i4], s5 = csr[i5], s6 = csr[i6];
                float4 g0 = *(const float4*)&base[(size_t)s0 * 64];
                float4 g1 = *(const float4*)&base[(size_t)s1 * 64];
                float4 g2 = *(const float4*)&base[(size_t)s2 * 64];
                float4 g3 = *(const float4*)&base[(size_t)s3 * 64];
                float4 g4 = *(const float4*)&base[(size_t)s4 * 64];
                float4 g5 = *(const float4*)&base[(size_t)s5 * 64];
                float4 g6 = *(const float4*)&base[(size_t)s6 * 64];
                acc.x += g0.x; acc.y += g0.y; acc.z += g0.z; acc.w += g0.w;
                acc.x = fmaf(m1, g1.x, acc.x); acc.y = fmaf(m1, g1.y, acc.y);
                acc.z = fmaf(m1, g1.z, acc.z); acc.w = fmaf(m1, g1.w, acc.w);
                acc.x = fmaf(m2, g2.x, acc.x); acc.y = fmaf(m2, g2.y, acc.y);
                acc.z = fmaf(m2, g2.z, acc.z); acc.w = fmaf(m2, g2.w, acc.w);
                acc.x = fmaf(m3, g3.x, acc.x); acc.y = fmaf(m3, g3.y, acc.y);
                acc.z = fmaf(m3, g3.z, acc.z); acc.w = fmaf(m3, g3.w, acc.w);
                acc.x = fmaf(m4, g4.x, acc.x); acc.y = fmaf(m4, g4.y, acc.y);
                acc.z = fmaf(m4, g4.z, acc.z); acc.w = fmaf(m4, g4.w, acc.w);
                acc.x = fmaf(m5, g5.x, acc.x); acc.y = fmaf(m5, g5.y, acc.y);
                acc.z = fmaf(m5, g5.z, acc.z); acc.w = fmaf(m5, g5.w, acc.w);
                acc.x = fmaf(m6, g6.x, acc.x); acc.y = fmaf(m6, g6.y, acc.y);
                acc.z = fmaf(m6, g6.z, acc.z); acc.w = fmaf(m6, g6.w, acc.w);
            }
            float4 h;
            h.x = di * acc.x + b4.x; h.x = h.x > 0.f ? h.x : 0.2f * h.x;
            h.y = di * acc.y + b4.y; h.y = h.y > 0.f ? h.y : 0.2f * h.y;
            h.z = di * acc.z + b4.z; h.z = h.z > 0.f ? h.z : 0.2f * h.z;
            h.w = di * acc.w + b4.w; h.w = h.w > 0.f ? h.w : 0.2f * h.w;
            *(float4*)&hL[row * 68 + 4 * lc] = h;
        }
    }
    __syncthreads();

    if (!LAST) {
        int rg = t >> 4;
        float4 a0, a1, a2, a3;
        a0 = a1 = a2 = a3 = make_float4(0.f, 0.f, 0.f, 0.f);
#pragma unroll 8
        for (int k = 0; k < 64; ++k) {
            float4 w = *(const float4*)&Wg[k * 64 + 4 * lc];
            float x0 = hL[(rg * 4 + 0) * 68 + k];
            float x1 = hL[(rg * 4 + 1) * 68 + k];
            float x2 = hL[(rg * 4 + 2) * 68 + k];
            float x3 = hL[(rg * 4 + 3) * 68 + k];
            a0.x = fmaf(x0, w.x, a0.x); a0.y = fmaf(x0, w.y, a0.y);
            a0.z = fmaf(x0, w.z, a0.z); a0.w = fmaf(x0, w.w, a0.w);
            a1.x = fmaf(x1, w.x, a1.x); a1.y = fmaf(x1, w.y, a1.y);
            a1.z = fmaf(x1, w.z, a1.z); a1.w = fmaf(x1, w.w, a1.w);
            a2.x = fmaf(x2, w.x, a2.x); a2.y = fmaf(x2, w.y, a2.y);
            a2.z = fmaf(x2, w.z, a2.z); a2.w = fmaf(x2, w.w, a2.w);
            a3.x = fmaf(x3, w.x, a3.x); a3.y = fmaf(x3, w.y, a3.y);
            a3.z = fmaf(x3, w.z, a3.z); a3.w = fmaf(x3, w.w, a3.w);
        }
#pragma unroll
        for (int r = 0; r < 4; ++r) {
            int v = vbase + rg * 4 + r;
            if (v < n) {
                float di = dinv[v];
                float4 a = (r == 0) ? a0 : (r == 1) ? a1 : (r == 2) ? a2 : a3;
                a.x *= di; a.y *= di; a.z *= di; a.w *= di;
                *(float4*)&hwout[(size_t)v * 64 + 4 * lc] = a;
            }
        }

        int sg = t >> 3, sc = t & 7;
        float4 s0, s1;
        s0 = s1 = make_float4(0.f, 0.f, 0.f, 0.f);
#pragma unroll 8
        for (int k = 0; k < 64; ++k) {
            float4 w = *(const float4*)&Ws[k * 32 + 4 * sc];
            float x0 = hL[(sg * 2 + 0) * 68 + k];
            float x1 = hL[(sg * 2 + 1) * 68 + k];
            s0.x = fmaf(x0, w.x, s0.x); s0.y = fmaf(x0, w.y, s0.y);
            s0.z = fmaf(x0, w.z, s0.z); s0.w = fmaf(x0, w.w, s0.w);
            s1.x = fmaf(x1, w.x, s1.x); s1.y = fmaf(x1, w.y, s1.y);
            s1.z = fmaf(x1, w.z, s1.z); s1.w = fmaf(x1, w.w, s1.w);
        }
#pragma unroll
        for (int r = 0; r < 2; ++r) {
            int v = vbase + sg * 2 + r;
            if (v < n) {
                float4 a = (r == 0) ? s0 : s1;
                float4* op = (float4*)(out + (size_t)v * 32 + 4 * sc);
                float4 o = *op;
                o.x += a.x; o.y += a.y; o.z += a.z; o.w += a.w;
                *op = o;
            }
        }
    } else {
        int sg = t >> 3, sc = t & 7;
        float4 s0, s1;
        s0 = s1 = make_float4(0.f, 0.f, 0.f, 0.f);
#pragma unroll 8
        for (int k = 0; k < 64; ++k) {
            float4 w = *(const float4*)&Ws[k * 32 + 4 * sc];  // Ws == Wl
            float x0 = hL[(sg * 2 + 0) * 68 + k];
            float x1 = hL[(sg * 2 + 1) * 68 + k];
            s0.x = fmaf(x0, w.x, s0.x); s0.y = fmaf(x0, w.y, s0.y);
            s0.z = fmaf(x0, w.z, s0.z); s0.w = fmaf(x0, w.w, s0.w);
            s1.x = fmaf(x1, w.x, s1.x); s1.y = fmaf(x1, w.y, s1.y);
            s1.z = fmaf(x1, w.z, s1.z); s1.w = fmaf(x1, w.w, s1.w);
        }
#pragma unroll
        for (int r = 0; r < 2; ++r) {
            int v = vbase + sg * 2 + r;
            if (v < n) {
                float di = dinv[v];
                float4 a = (r == 0) ? s0 : s1;
                a.x *= di; a.y *= di; a.z *= di; a.w *= di;
                *(float4*)&hwout[(size_t)v * 32 + 4 * sc] = a;
            }
        }
    }
}

// ---------------- final gather into output (32 ch, 8 lanes/node) ----------------

__global__ __launch_bounds__(256) void gather_out_kernel(
        const int* __restrict__ rowstart, const int* __restrict__ csr,
        const float* __restrict__ dinv, const float* __restrict__ hwl,
        float* __restrict__ out, int n) {
    int t = threadIdx.x;
    int lr = t >> 3, lc = t & 7;
    int v = blockIdx.x * 32 + lr;
    if (v >= n) return;
    int beg = rowstart[v], end = rowstart[v + 1];
    float4 acc = *(const float4*)&hwl[(size_t)v * 32 + 4 * lc];
    const float* base = hwl + 4 * lc;
    int e = beg;
    for (; e + 8 <= end; e += 8) {
        int s0 = csr[e + 0], s1 = csr[e + 1], s2 = csr[e + 2], s3 = csr[e + 3];
        int s4 = csr[e + 4], s5 = csr[e + 5], s6 = csr[e + 6], s7 = csr[e + 7];
        float4 g0 = *(const float4*)&base[(size_t)s0 * 32];
        float4 g1 = *(const float4*)&base[(size_t)s1 * 32];
        float4 g2 = *(const float4*)&base[(size_t)s2 * 32];
        float4 g3 = *(const float4*)&base[(size_t)s3 * 32];
        float4 g4 = *(const float4*)&base[(size_t)s4 * 32];
        float4 g5 = *(const float4*)&base[(size_t)s5 * 32];
        float4 g6 = *(const float4*)&base[(size_t)s6 * 32];
        float4 g7 = *(const float4*)&base[(size_t)s7 * 32];
        acc.x += ((g0.x + g1.x) + (g2.x + g3.x)) + ((g4.x + g5.x) + (g6.x + g7.x));
        acc.y += ((g0.y + g1.y) + (g2.y + g3.y)) + ((g4.y + g5.y) + (g6.y + g7.y));
        acc.z += ((g0.z + g1.z) + (g2.z + g3.z)) + ((g4.z + g5.z) + (g6.z + g7.z));
        acc.w += ((g0.w + g1.w) + (g2.w + g3.w)) + ((g4.w + g5.w) + (g6.w + g7.w));
    }
    if (e < end) {
        int last = end - 1;
        int i1 = min(e + 1, last), i2 = min(e + 2, last), i3 = min(e + 3, last);
        int i4 = min(e + 4, last), i5 = min(e + 5, last), i6 = min(e + 6, last);
        float m1 = (e + 1 < end) ? 1.f : 0.f;
        float m2 = (e + 2 < end) ? 1.f : 0.f;
        float m3 = (e + 3 < end) ? 1.f : 0.f;
        float m4 = (e + 4 < end) ? 1.f : 0.f;
        float m5 = (e + 5 < end) ? 1.f : 0.f;
        float m6 = (e + 6 < end) ? 1.f : 0.f;
        int s0 = csr[e], s1 = csr[i1], s2 = csr[i2], s3 = csr[i3];
        int s4 = csr[i4], s5 = csr[i5], s6 = csr[i6];
        float4 g0 = *(const float4*)&base[(size_t)s0 * 32];
        float4 g1 = *(const float4*)&base[(size_t)s1 * 32];
        float4 g2 = *(const float4*)&base[(size_t)s2 * 32];
        float4 g3 = *(const float4*)&base[(size_t)s3 * 32];
        float4 g4 = *(const float4*)&base[(size_t)s4 * 32];
        float4 g5 = *(const float4*)&base[(size_t)s5 * 32];
        float4 g6 = *(const float4*)&base[(size_t)s6 * 32];
        acc.x += g0.x; acc.y += g0.y; acc.z += g0.z; acc.w += g0.w;
        acc.x = fmaf(m1, g1.x, acc.x); acc.y = fmaf(m1, g1.y, acc.y);
        acc.z = fmaf(m1, g1.z, acc.z); acc.w = fmaf(m1, g1.w, acc.w);
        acc.x = fmaf(m2, g2.x, acc.x); acc.y = fmaf(m2, g2.y, acc.y);
        acc.z = fmaf(m2, g2.z, acc.z); acc.w = fmaf(m2, g2.w, acc.w);
        acc.x = fmaf(m3, g3.x, acc.x); acc.y = fmaf(m3, g3.y, acc.y);
        acc.z = fmaf(m3, g3.z, acc.z); acc.w = fmaf(m3, g3.w, acc.w);
        acc.x = fmaf(m4, g4.x, acc.x); acc.y = fmaf(m4, g4.y, acc.y);
        acc.z = fmaf(m4, g4.z, acc.z); acc.w = fmaf(m4, g4.w, acc.w);
        acc.x = fmaf(m5, g5.x, acc.x); acc.y = fmaf(m5, g5.y, acc.y);
        acc.z = fmaf(m5, g5.z, acc.z); acc.w = fmaf(m5, g5.w, acc.w);
        acc.x = fmaf(m6, g6.x, acc.x); acc.y = fmaf(m6, g6.y, acc.y);
        acc.z = fmaf(m6, g6.z, acc.z); acc.w = fmaf(m6, g6.w, acc.w);
    }
    float di = dinv[v];
    float4* op = (float4*)(out + (size_t)v * 32 + 4 * lc);
    float4 o = *op;
    o.x += di * acc.x; o.y += di * acc.y; o.z += di * acc.z; o.w += di * acc.w;
    *op = o;
}

// ---------------- launch ----------------

extern "C" void kernel_launch(void* const* d_in, const int* in_sizes, int n_in,
                              void* d_out, int out_size, void* d_ws, size_t ws_size,
                              hipStream_t stream) {
    const float* x    = (const float*)d_in[0];
    const int*   ei   = (const int*)d_in[1];
    const float* W_in = (const float*)d_in[2];
    const float* b_in = (const float*)d_in[3];
    const float* Wg   = (const float*)d_in[4];  // [3][64][64]
    const float* bg   = (const float*)d_in[5];  // [3][64]
    const float* Ws   = (const float*)d_in[6];  // [3][64][32]
    const float* bs   = (const float*)d_in[7];  // [3][32]
    const float* Wl   = (const float*)d_in[8];  // [64][32]
    const float* bl   = (const float*)d_in[9];  // [32]

    const int N = in_sizes[0] / 128;
    const int E = in_sizes[1] / 2;
    const int nb1 = cdiv(N, 128);
    const int chunk = cdiv(E, PW);
    const int* srcp = ei;
    const int* dstp = ei + E;

    char* p = (char*)d_ws;
    float*    hwA      = (float*)p;    p += (size_t)N * HID * 4;
    float*    hwB      = (float*)p;    p += (size_t)N * HID * 4;
    unsigned* bbuf     = (unsigned*)p; p += (size_t)E * 4;
    int*      csr      = (int*)p;      p += (size_t)E * 4;
    int*      rowstart = (int*)p;      p += ((size_t)N + 1) * 4;
    float*    dinv     = (float*)p;    p += (size_t)N * 4;
    int*      hist     = (int*)p;      p += (size_t)nb1 * PW * 4;
    int*      colpre   = (int*)p;      p += (size_t)nb1 * PW * 4;
    int*      btot     = (int*)p;      p += (size_t)nb1 * 4;
    int*      bstart   = (int*)p;      p += ((size_t)nb1 + 1) * 4;
    float*    out      = (float*)d_out;

    const int B = 256;

    hist_kernel<<<PW, B, 0, stream>>>(dstp, hist, E, nb1, chunk);
    colscan_kernel<<<nb1, PW, 0, stream>>>(hist, colpre, btot);
    bscan_kernel<<<1, 1024, 0, stream>>>(btot, bstart, nb1, E);
    partition_kernel<<<PW, B, 0, stream>>>(srcp, dstp, bstart, colpre, bbuf, E, nb1, chunk);
    build_csr_kernel<<<nb1, B, 0, stream>>>(bstart, bbuf, csr, rowstart, dinv, N, E);

    input_fused_kernel<<<cdiv(N, 64), B, 0, stream>>>(
        x, W_in, b_in, Wg, Ws, dinv, bl, bs, hwA, out, N);

    gather_transform_kernel<false><<<cdiv(N, 64), B, 0, stream>>>(
        rowstart, csr, dinv, hwA, bg, Wg + 4096, Ws + 2048, hwB, out, N);

    gather_transform_kernel<false><<<cdiv(N, 64), B, 0, stream>>>(
        rowstart, csr, dinv, hwB, bg + 64, Wg + 8192, Ws + 4096, hwA, out, N);

    gather_transform_kernel<true><<<cdiv(N, 64), B, 0, stream>>>(
        rowstart, csr, dinv, hwA, bg + 128, nullptr, Wl, hwB, nullptr, N);

    gather_out_kernel<<<cdiv(N, 32), B, 0, stream>>>(rowstart, csr, dinv, hwB, out, N);
}

// Round 12
// 491.611 us; speedup vs baseline: 1.3268x; 1.0086x over previous
//
#include <hip/hip_runtime.h>

// GCN encoder, fused gather formulation + radix-partition CSR build.
// Measured models (MI355X):
//  - same-address atomic chain ~184ns/op (r3).
//  - cross-XCD line sharing on scatter/append => no write-combining (r2/r7).
//    Fix: radix partition, per-WG exclusive output runs (r9).
//  - 1-output/thread dense = latency-stalled (r5) -> 4x4 register tiling.
//  - big LDS kills occupancy (r6: 50KB -> 3 blocks/CU) -> keep LDS <= ~34KB.
//  - r11: per-lane gather unroll 4->8 was ~neutral -> gather NOT per-lane-MLP
//    bound; overhead = csr scalar loads (8 instr / 8 edges) + masked tail +
//    divergence. Fix: pad CSR rows to x8 with sentinel node n (zero message
//    row) -> exact 8-wide loop, csr via int4 (2 instr / 8 edges), no masks.
//  - input_fused thin x loads (64B/wave broadcast) -> stream x through LDS in
//    32-col double-buffered chunks (coalesced 1KB/wave stages, latency hidden
//    under previous chunk's FMAs).
// Pipeline (10 dispatches):
//   hist | colscan | bscan | partition | build_csr(padded)
//   K0 : h0=x@Win+b -> {out = allbias + h0@Ws0, hwA=(h0@Wg0)*dinv}; zero hwA[n]
//   GT1: gather(hwA)->h1 -> {out+=h1@Ws1, hwB=(h1@Wg1)*dinv}; zero hwB[n]
//   GT2: gather(hwB)->h2 -> {out+=h2@Ws2, hwA=(h2@Wg2)*dinv}
//   GT3: gather(hwA)->h3 -> hwB32=(h3@Wl)*dinv; zero hwB32[n]
//   GO : out += dinv * gather32(hwB32)
// Identity: gcn(h)[v] = dinv[v] * sum_{s in nbr(v) u {v}} (hW*dinv)[s] + b

#define HID 64
#define LAT 32
#define PW 128         // partition WGs
#define CCAP 3456      // padded csr capacity per 128-node bucket (mean ~2496, +8sigma+maxpad safe)

static inline int cdiv(long long a, long long b) { return (int)((a + b - 1) / b); }

// ---------------- CSR build: radix partition by dst>>7 ----------------

__global__ __launch_bounds__(256) void hist_kernel(const int* __restrict__ dst,
                                                   int* __restrict__ hist,
                                                   int E, int nb1, int chunk) {
    __shared__ int h[1024];
    int w = blockIdx.x, t = threadIdx.x;
    for (int i = t; i < nb1; i += 256) h[i] = 0;
    __syncthreads();
    int beg = w * chunk, end = min(E, beg + chunk);
    for (int e = beg + t; e < end; e += 256) atomicAdd(&h[dst[e] >> 7], 1);
    __syncthreads();
    for (int i = t; i < nb1; i += 256) hist[i * PW + w] = h[i];
}

__global__ __launch_bounds__(PW) void colscan_kernel(const int* __restrict__ hist,
                                                     int* __restrict__ colprefix,
                                                     int* __restrict__ btot) {
    __shared__ int s[PW];
    int b = blockIdx.x, t = threadIdx.x;
    int v = hist[b * PW + t];
    s[t] = v;
    __syncthreads();
    for (int off = 1; off < PW; off <<= 1) {
        int x = (t >= off) ? s[t - off] : 0;
        __syncthreads();
        s[t] += x;
        __syncthreads();
    }
    colprefix[b * PW + t] = s[t] - v;
    if (t == PW - 1) btot[b] = s[t];
}

__global__ __launch_bounds__(1024) void bscan_kernel(const int* __restrict__ btot,
                                                     int* __restrict__ bstart, int nb1, int E) {
    __shared__ int s[1024];
    int t = threadIdx.x;
    int v = (t < nb1) ? btot[t] : 0;
    s[t] = v;
    __syncthreads();
    for (int off = 1; off < 1024; off <<= 1) {
        int x = (t >= off) ? s[t - off] : 0;
        __syncthreads();
        s[t] += x;
        __syncthreads();
    }
    if (t < nb1) bstart[t] = s[t] - v;
    if (t == 0) bstart[nb1] = E;
}

__global__ __launch_bounds__(256) void partition_kernel(
        const int* __restrict__ src, const int* __restrict__ dst,
        const int* __restrict__ bstart, const int* __restrict__ colprefix,
        unsigned* __restrict__ bbuf, int E, int nb1, int chunk) {
    __shared__ int cur[1024];
    int w = blockIdx.x, t = threadIdx.x;
    for (int i = t; i < nb1; i += 256) cur[i] = bstart[i] + colprefix[i * PW + w];
    __syncthreads();
    int beg = w * chunk, end = min(E, beg + chunk);
    for (int e = beg + t; e < end; e += 256) {
        int s = src[e], d = dst[e];
        int pos = atomicAdd(&cur[d >> 7], 1);
        bbuf[pos] = ((unsigned)(d & 127) << 17) | (unsigned)s;
    }
}

// per-bucket: counts -> padded prefix (x8) -> scatter -> sentinel pad fill.
// csr row v occupies [rowbeg[v], rowend[v]), multiple of 8, sentinel = n.
__global__ __launch_bounds__(256) void build_csr_kernel(
        const int* __restrict__ bstart, const unsigned* __restrict__ bbuf,
        int* __restrict__ csr, int* __restrict__ rowbeg, int* __restrict__ rowend,
        float* __restrict__ dinv, int n) {
    __shared__ int lcount[128], lpre[128], lcur[128];
    int b = blockIdx.x, t = threadIdx.x;
    int bst = bstart[b], bend = bstart[b + 1];
    int base = b * CCAP;

    if (t < 128) lcount[t] = 0;
    __syncthreads();
    for (int i = bst + t; i < bend; i += 256) atomicAdd(&lcount[bbuf[i] >> 17], 1);
    __syncthreads();
    if (t == 0) {
        int run = 0;
        for (int k = 0; k < 128; ++k) {
            lpre[k] = run;
            lcur[k] = run;
            run += (lcount[k] + 7) & ~7;
        }
    }
    __syncthreads();
    if (t < 128) {
        int v = (b << 7) + t;
        if (v < n) {
            int beg = base + lpre[t];
            rowbeg[v] = beg;
            rowend[v] = beg + ((lcount[t] + 7) & ~7);
            dinv[v] = rsqrtf((float)(lcount[t] + 1));
        }
    }
    for (int i = bst + t; i < bend; i += 256) {
        unsigned p = bbuf[i];
        int pos = base + atomicAdd(&lcur[p >> 17], 1);
        csr[pos] = (int)(p & 0x1FFFFu);
    }
    __syncthreads();
    if (t < 128) {
        int s = base + lpre[t] + lcount[t];
        int epad = base + lpre[t] + ((lcount[t] + 7) & ~7);
        for (int i = s; i < epad; ++i) csr[i] = n;  // sentinel -> zero message row
    }
}

// ---------------- K0: input layer, streamed-LDS x, 4x4 tiled ----------------
// 64 rows/block. Phase1: x staged in 32-col chunks (2x 8.4KB double buffer,
// coalesced stage loads hidden under previous chunk's FMAs). Phase2a:
// hw=(h0@Wg0)*dinv. Phase2b: out = allbias + h0@Ws0. Zeros sentinel hw row n.

__global__ __launch_bounds__(256) void input_fused_kernel(
        const float* __restrict__ x, const float* __restrict__ Win,
        const float* __restrict__ bin, const float* __restrict__ Wg0,
        const float* __restrict__ Ws0, const float* __restrict__ dinv,
        const float* __restrict__ bl, const float* __restrict__ bs,
        float* __restrict__ hw, float* __restrict__ out, int n) {
    __shared__ float xs[2][64 * 33];  // stride 33: rg-group rows hit distinct banks
    __shared__ float h0[64 * 68];     // stride 68: 2-way alias (free), 16B rows
    int t = threadIdx.x;
    int vbase = blockIdx.x * 64;
    int rg = t >> 4, lc = t & 15;

    if (blockIdx.x == 0 && t < 64) hw[(size_t)n * 64 + t] = 0.f;  // sentinel row

    // stage addressing: thread t loads rows srow, srow+32 at cols scol..scol+3
    int srow = t >> 3, scol = (t & 7) * 4;
    long long gr0 = vbase + srow;      if (gr0 >= n) gr0 = n - 1;
    long long gr1 = vbase + srow + 32; if (gr1 >= n) gr1 = n - 1;
    const float* gp0 = x + gr0 * 128 + scol;
    const float* gp1 = x + gr1 * 128 + scol;

    float4 p0 = *(const float4*)&gp0[0];
    float4 p1 = *(const float4*)&gp1[0];
    *(float4*)&xs[0][srow * 33 + scol] = p0;
    *(float4*)&xs[0][(srow + 32) * 33 + scol] = p1;
    __syncthreads();

    float4 b4 = *(const float4*)&bin[4 * lc];
    float4 a0 = b4, a1 = b4, a2 = b4, a3 = b4;
#pragma unroll
    for (int c = 0; c < 4; ++c) {
        if (c < 3) {  // issue next-chunk loads; latency hides under FMAs below
            p0 = *(const float4*)&gp0[(c + 1) * 32];
            p1 = *(const float4*)&gp1[(c + 1) * 32];
        }
        const float* xb = xs[c & 1];
        const float* wb = Win + (size_t)c * 32 * 64;
#pragma unroll
        for (int kk = 0; kk < 32; ++kk) {
            float4 w = *(const float4*)&wb[kk * 64 + 4 * lc];
            float x0 = xb[(rg * 4 + 0) * 33 + kk];
            float x1 = xb[(rg * 4 + 1) * 33 + kk];
            float x2 = xb[(rg * 4 + 2) * 33 + kk];
            float x3 = xb[(rg * 4 + 3) * 33 + kk];
            a0.x = fmaf(x0, w.x, a0.x); a0.y = fmaf(x0, w.y, a0.y);
            a0.z = fmaf(x0, w.z, a0.z); a0.w = fmaf(x0, w.w, a0.w);
            a1.x = fmaf(x1, w.x, a1.x); a1.y = fmaf(x1, w.y, a1.y);
            a1.z = fmaf(x1, w.z, a1.z); a1.w = fmaf(x1, w.w, a1.w);
            a2.x = fmaf(x2, w.x, a2.x); a2.y = fmaf(x2, w.y, a2.y);
            a2.z = fmaf(x2, w.z, a2.z); a2.w = fmaf(x2, w.w, a2.w);
            a3.x = fmaf(x3, w.x, a3.x); a3.y = fmaf(x3, w.y, a3.y);
            a3.z = fmaf(x3, w.z, a3.z); a3.w = fmaf(x3, w.w, a3.w);
        }
        if (c < 3) {
            *(float4*)&xs[(c + 1) & 1][srow * 33 + scol] = p0;
            *(float4*)&xs[(c + 1) & 1][(srow + 32) * 33 + scol] = p1;
            __syncthreads();
        }
    }
    *(float4*)&h0[(rg * 4 + 0) * 68 + 4 * lc] = a0;
    *(float4*)&h0[(rg * 4 + 1) * 68 + 4 * lc] = a1;
    *(float4*)&h0[(rg * 4 + 2) * 68 + 4 * lc] = a2;
    *(float4*)&h0[(rg * 4 + 3) * 68 + 4 * lc] = a3;
    __syncthreads();

    // Phase2a: hw = (h0 @ Wg0) * dinv
    {
        float4 c0, c1, c2, c3;
        c0 = c1 = c2 = c3 = make_float4(0.f, 0.f, 0.f, 0.f);
#pragma unroll 8
        for (int k = 0; k < 64; ++k) {
            float4 w = *(const float4*)&Wg0[k * 64 + 4 * lc];
            float x0 = h0[(rg * 4 + 0) * 68 + k];
            float x1 = h0[(rg * 4 + 1) * 68 + k];
            float x2 = h0[(rg * 4 + 2) * 68 + k];
            float x3 = h0[(rg * 4 + 3) * 68 + k];
            c0.x = fmaf(x0, w.x, c0.x); c0.y = fmaf(x0, w.y, c0.y);
            c0.z = fmaf(x0, w.z, c0.z); c0.w = fmaf(x0, w.w, c0.w);
            c1.x = fmaf(x1, w.x, c1.x); c1.y = fmaf(x1, w.y, c1.y);
            c1.z = fmaf(x1, w.z, c1.z); c1.w = fmaf(x1, w.w, c1.w);
            c2.x = fmaf(x2, w.x, c2.x); c2.y = fmaf(x2, w.y, c2.y);
            c2.z = fmaf(x2, w.z, c2.z); c2.w = fmaf(x2, w.w, c2.w);
            c3.x = fmaf(x3, w.x, c3.x); c3.y = fmaf(x3, w.y, c3.y);
            c3.z = fmaf(x3, w.z, c3.z); c3.w = fmaf(x3, w.w, c3.w);
        }
#pragma unroll
        for (int r = 0; r < 4; ++r) {
            int v = vbase + rg * 4 + r;
            if (v < n) {
                float di = dinv[v];
                float4 a = (r == 0) ? c0 : (r == 1) ? c1 : (r == 2) ? c2 : c3;
                a.x *= di; a.y *= di; a.z *= di; a.w *= di;
                *(float4*)&hw[(size_t)v * 64 + 4 * lc] = a;
            }
        }
    }

    // Phase2b: out = (bl + sum bs) + h0 @ Ws0
    {
        int sg = t >> 3, sc = t & 7;
        float4 bb = *(const float4*)&bl[4 * sc];
        float4 q0 = *(const float4*)&bs[4 * sc];
        float4 q1 = *(const float4*)&bs[LAT + 4 * sc];
        float4 q2 = *(const float4*)&bs[2 * LAT + 4 * sc];
        bb.x += q0.x + q1.x + q2.x; bb.y += q0.y + q1.y + q2.y;
        bb.z += q0.z + q1.z + q2.z; bb.w += q0.w + q1.w + q2.w;
        float4 s0 = bb, s1 = bb;
#pragma unroll 8
        for (int k = 0; k < 64; ++k) {
            float4 w = *(const float4*)&Ws0[k * 32 + 4 * sc];
            float x0 = h0[(sg * 2 + 0) * 68 + k];
            float x1 = h0[(sg * 2 + 1) * 68 + k];
            s0.x = fmaf(x0, w.x, s0.x); s0.y = fmaf(x0, w.y, s0.y);
            s0.z = fmaf(x0, w.z, s0.z); s0.w = fmaf(x0, w.w, s0.w);
            s1.x = fmaf(x1, w.x, s1.x); s1.y = fmaf(x1, w.y, s1.y);
            s1.z = fmaf(x1, w.z, s1.z); s1.w = fmaf(x1, w.w, s1.w);
        }
#pragma unroll
        for (int r = 0; r < 2; ++r) {
            int v = vbase + sg * 2 + r;
            if (v < n)
                *(float4*)&out[(size_t)v * 32 + 4 * sc] = (r == 0) ? s0 : s1;
        }
    }
}

// ---------------- fused gather + transform, 64 nodes/block ----------------
// Padded CSR: exact 8-wide loop, csr via int4, no masks, no tail.

template <bool LAST>
__global__ __launch_bounds__(256) void gather_transform_kernel(
        const int* __restrict__ rowbeg, const int* __restrict__ rowend,
        const int* __restrict__ csr, const float* __restrict__ dinv,
        const float* __restrict__ hwin, const float* __restrict__ bias,
        const float* __restrict__ Wg, const float* __restrict__ Ws,
        float* __restrict__ hwout, float* __restrict__ out, int n) {
    __shared__ float hL[64 * 68];
    int t = threadIdx.x;
    int vbase = blockIdx.x * 64;
    int ns = t >> 4, lc = t & 15;

    if (blockIdx.x == 0) {  // zero next sentinel row
        if (!LAST) { if (t < 64) hwout[(size_t)n * 64 + t] = 0.f; }
        else       { if (t < 32) hwout[(size_t)n * 32 + t] = 0.f; }
    }

    float4 b4 = *(const float4*)&bias[4 * lc];
#pragma unroll
    for (int b = 0; b < 4; ++b) {
        int row = b * 16 + ns;
        int v = vbase + row;
        if (v < n) {
            int beg = rowbeg[v], end = rowend[v];
            float di = dinv[v];
            float4 acc = *(const float4*)&hwin[(size_t)v * 64 + 4 * lc];  // self
            const float* base = hwin + 4 * lc;
            for (int e = beg; e < end; e += 8) {
                int4 ca = *(const int4*)&csr[e];
                int4 cb = *(const int4*)&csr[e + 4];
                float4 g0 = *(const float4*)&base[(size_t)ca.x * 64];
                float4 g1 = *(const float4*)&base[(size_t)ca.y * 64];
                float4 g2 = *(const float4*)&base[(size_t)ca.z * 64];
                float4 g3 = *(const float4*)&base[(size_t)ca.w * 64];
                float4 g4 = *(const float4*)&base[(size_t)cb.x * 64];
                float4 g5 = *(const float4*)&base[(size_t)cb.y * 64];
                float4 g6 = *(const float4*)&base[(size_t)cb.z * 64];
                float4 g7 = *(const float4*)&base[(size_t)cb.w * 64];
                acc.x += ((g0.x + g1.x) + (g2.x + g3.x)) + ((g4.x + g5.x) + (g6.x + g7.x));
                acc.y += ((g0.y + g1.y) + (g2.y + g3.y)) + ((g4.y + g5.y) + (g6.y + g7.y));
                acc.z += ((g0.z + g1.z) + (g2.z + g3.z)) + ((g4.z + g5.z) + (g6.z + g7.z));
                acc.w += ((g0.w + g1.w) + (g2.w + g3.w)) + ((g4.w + g5.w) + (g6.w + g7.w));
            }
            float4 h;
            h.x = di * acc.x + b4.x; h.x = h.x > 0.f ? h.x : 0.2f * h.x;
            h.y = di * acc.y + b4.y; h.y = h.y > 0.f ? h.y : 0.2f * h.y;
            h.z = di * acc.z + b4.z; h.z = h.z > 0.f ? h.z : 0.2f * h.z;
            h.w = di * acc.w + b4.w; h.w = h.w > 0.f ? h.w : 0.2f * h.w;
            *(float4*)&hL[row * 68 + 4 * lc] = h;
        }
    }
    __syncthreads();

    if (!LAST) {
        int rg = t >> 4;
        float4 c0, c1, c2, c3;
        c0 = c1 = c2 = c3 = make_float4(0.f, 0.f, 0.f, 0.f);
#pragma unroll 8
        for (int k = 0; k < 64; ++k) {
            float4 w = *(const float4*)&Wg[k * 64 + 4 * lc];
            float x0 = hL[(rg * 4 + 0) * 68 + k];
            float x1 = hL[(rg * 4 + 1) * 68 + k];
            float x2 = hL[(rg * 4 + 2) * 68 + k];
            float x3 = hL[(rg * 4 + 3) * 68 + k];
            c0.x = fmaf(x0, w.x, c0.x); c0.y = fmaf(x0, w.y, c0.y);
            c0.z = fmaf(x0, w.z, c0.z); c0.w = fmaf(x0, w.w, c0.w);
            c1.x = fmaf(x1, w.x, c1.x); c1.y = fmaf(x1, w.y, c1.y);
            c1.z = fmaf(x1, w.z, c1.z); c1.w = fmaf(x1, w.w, c1.w);
            c2.x = fmaf(x2, w.x, c2.x); c2.y = fmaf(x2, w.y, c2.y);
            c2.z = fmaf(x2, w.z, c2.z); c2.w = fmaf(x2, w.w, c2.w);
            c3.x = fmaf(x3, w.x, c3.x); c3.y = fmaf(x3, w.y, c3.y);
            c3.z = fmaf(x3, w.z, c3.z); c3.w = fmaf(x3, w.w, c3.w);
        }
#pragma unroll
        for (int r = 0; r < 4; ++r) {
            int v = vbase + rg * 4 + r;
            if (v < n) {
                float di = dinv[v];
                float4 a = (r == 0) ? c0 : (r == 1) ? c1 : (r == 2) ? c2 : c3;
                a.x *= di; a.y *= di; a.z *= di; a.w *= di;
                *(float4*)&hwout[(size_t)v * 64 + 4 * lc] = a;
            }
        }

        int sg = t >> 3, sc = t & 7;
        float4 s0, s1;
        s0 = s1 = make_float4(0.f, 0.f, 0.f, 0.f);
#pragma unroll 8
        for (int k = 0; k < 64; ++k) {
            float4 w = *(const float4*)&Ws[k * 32 + 4 * sc];
            float x0 = hL[(sg * 2 + 0) * 68 + k];
            float x1 = hL[(sg * 2 + 1) * 68 + k];
            s0.x = fmaf(x0, w.x, s0.x); s0.y = fmaf(x0, w.y, s0.y);
            s0.z = fmaf(x0, w.z, s0.z); s0.w = fmaf(x0, w.w, s0.w);
            s1.x = fmaf(x1, w.x, s1.x); s1.y = fmaf(x1, w.y, s1.y);
            s1.z = fmaf(x1, w.z, s1.z); s1.w = fmaf(x1, w.w, s1.w);
        }
#pragma unroll
        for (int r = 0; r < 2; ++r) {
            int v = vbase + sg * 2 + r;
            if (v < n) {
                float4 a = (r == 0) ? s0 : s1;
                float4* op = (float4*)(out + (size_t)v * 32 + 4 * sc);
                float4 o = *op;
                o.x += a.x; o.y += a.y; o.z += a.z; o.w += a.w;
                *op = o;
            }
        }
    } else {
        int sg = t >> 3, sc = t & 7;
        float4 s0, s1;
        s0 = s1 = make_float4(0.f, 0.f, 0.f, 0.f);
#pragma unroll 8
        for (int k = 0; k < 64; ++k) {
            float4 w = *(const float4*)&Ws[k * 32 + 4 * sc];  // Ws == Wl
            float x0 = hL[(sg * 2 + 0) * 68 + k];
            float x1 = hL[(sg * 2 + 1) * 68 + k];
            s0.x = fmaf(x0, w.x, s0.x); s0.y = fmaf(x0, w.y, s0.y);
            s0.z = fmaf(x0, w.z, s0.z); s0.w = fmaf(x0, w.w, s0.w);
            s1.x = fmaf(x1, w.x, s1.x); s1.y = fmaf(x1, w.y, s1.y);
            s1.z = fmaf(x1, w.z, s1.z); s1.w = fmaf(x1, w.w, s1.w);
        }
#pragma unroll
        for (int r = 0; r < 2; ++r) {
            int v = vbase + sg * 2 + r;
            if (v < n) {
                float di = dinv[v];
                float4 a = (r == 0) ? s0 : s1;
                a.x *= di; a.y *= di; a.z *= di; a.w *= di;
                *(float4*)&hwout[(size_t)v * 32 + 4 * sc] = a;
            }
        }
    }
}

// ---------------- final gather into output (32 ch, 8 lanes/node) ----------------

__global__ __launch_bounds__(256) void gather_out_kernel(
        const int* __restrict__ rowbeg, const int* __restrict__ rowend,
        const int* __restrict__ csr, const float* __restrict__ dinv,
        const float* __restrict__ hwl, float* __restrict__ out, int n) {
    int t = threadIdx.x;
    int lr = t >> 3, lc = t & 7;
    int v = blockIdx.x * 32 + lr;
    if (v >= n) return;
    int beg = rowbeg[v], end = rowend[v];
    float4 acc = *(const float4*)&hwl[(size_t)v * 32 + 4 * lc];
    const float* base = hwl + 4 * lc;
    for (int e = beg; e < end; e += 8) {
        int4 ca = *(const int4*)&csr[e];
        int4 cb = *(const int4*)&csr[e + 4];
        float4 g0 = *(const float4*)&base[(size_t)ca.x * 32];
        float4 g1 = *(const float4*)&base[(size_t)ca.y * 32];
        float4 g2 = *(const float4*)&base[(size_t)ca.z * 32];
        float4 g3 = *(const float4*)&base[(size_t)ca.w * 32];
        float4 g4 = *(const float4*)&base[(size_t)cb.x * 32];
        float4 g5 = *(const float4*)&base[(size_t)cb.y * 32];
        float4 g6 = *(const float4*)&base[(size_t)cb.z * 32];
        float4 g7 = *(const float4*)&base[(size_t)cb.w * 32];
        acc.x += ((g0.x + g1.x) + (g2.x + g3.x)) + ((g4.x + g5.x) + (g6.x + g7.x));
        acc.y += ((g0.y + g1.y) + (g2.y + g3.y)) + ((g4.y + g5.y) + (g6.y + g7.y));
        acc.z += ((g0.z + g1.z) + (g2.z + g3.z)) + ((g4.z + g5.z) + (g6.z + g7.z));
        acc.w += ((g0.w + g1.w) + (g2.w + g3.w)) + ((g4.w + g5.w) + (g6.w + g7.w));
    }
    float di = dinv[v];
    float4* op = (float4*)(out + (size_t)v * 32 + 4 * lc);
    float4 o = *op;
    o.x += di * acc.x; o.y += di * acc.y; o.z += di * acc.z; o.w += di * acc.w;
    *op = o;
}

// ---------------- launch ----------------

extern "C" void kernel_launch(void* const* d_in, const int* in_sizes, int n_in,
                              void* d_out, int out_size, void* d_ws, size_t ws_size,
                              hipStream_t stream) {
    const float* x    = (const float*)d_in[0];
    const int*   ei   = (const int*)d_in[1];
    const float* W_in = (const float*)d_in[2];
    const float* b_in = (const float*)d_in[3];
    const float* Wg   = (const float*)d_in[4];  // [3][64][64]
    const float* bg   = (const float*)d_in[5];  // [3][64]
    const float* Ws   = (const float*)d_in[6];  // [3][64][32]
    const float* bs   = (const float*)d_in[7];  // [3][32]
    const float* Wl   = (const float*)d_in[8];  // [64][32]
    const float* bl   = (const float*)d_in[9];  // [32]

    const int N = in_sizes[0] / 128;
    const int E = in_sizes[1] / 2;
    const int nb1 = cdiv(N, 128);
    const int chunk = cdiv(E, PW);
    const int* srcp = ei;
    const int* dstp = ei + E;

    char* p = (char*)d_ws;
    float*    hwA      = (float*)p;    p += ((size_t)N + 1) * HID * 4;
    float*    hwB      = (float*)p;    p += ((size_t)N + 1) * HID * 4;
    unsigned* bbuf     = (unsigned*)p; p += (size_t)E * 4;
    int*      csr      = (int*)p;      p += (size_t)nb1 * CCAP * 4;
    int*      rowbeg   = (int*)p;      p += (size_t)N * 4;
    int*      rowend   = (int*)p;      p += (size_t)N * 4;
    float*    dinv     = (float*)p;    p += (size_t)N * 4;
    int*      hist     = (int*)p;      p += (size_t)nb1 * PW * 4;
    int*      colpre   = (int*)p;      p += (size_t)nb1 * PW * 4;
    int*      btot     = (int*)p;      p += (size_t)nb1 * 4;
    int*      bstart   = (int*)p;      p += ((size_t)nb1 + 1) * 4;
    float*    out      = (float*)d_out;

    const int B = 256;

    hist_kernel<<<PW, B, 0, stream>>>(dstp, hist, E, nb1, chunk);
    colscan_kernel<<<nb1, PW, 0, stream>>>(hist, colpre, btot);
    bscan_kernel<<<1, 1024, 0, stream>>>(btot, bstart, nb1, E);
    partition_kernel<<<PW, B, 0, stream>>>(srcp, dstp, bstart, colpre, bbuf, E, nb1, chunk);
    build_csr_kernel<<<nb1, B, 0, stream>>>(bstart, bbuf, csr, rowbeg, rowend, dinv, N);

    input_fused_kernel<<<cdiv(N, 64), B, 0, stream>>>(
        x, W_in, b_in, Wg, Ws, dinv, bl, bs, hwA, out, N);

    gather_transform_kernel<false><<<cdiv(N, 64), B, 0, stream>>>(
        rowbeg, rowend, csr, dinv, hwA, bg, Wg + 4096, Ws + 2048, hwB, out, N);

    gather_transform_kernel<false><<<cdiv(N, 64), B, 0, stream>>>(
        rowbeg, rowend, csr, dinv, hwB, bg + 64, Wg + 8192, Ws + 4096, hwA, out, N);

    gather_transform_kernel<true><<<cdiv(N, 64), B, 0, stream>>>(
        rowbeg, rowend, csr, dinv, hwA, bg + 128, nullptr, Wl, hwB, nullptr, N);

    gather_out_kernel<<<cdiv(N, 32), B, 0, stream>>>(rowbeg, rowend, csr, dinv, hwB, out, N);
}

// Round 14
// 423.145 us; speedup vs baseline: 1.5415x; 1.1618x over previous
//
#include <hip/hip_runtime.h>

// GCN encoder, fused gather formulation + radix-partition CSR build.
// Measured models (MI355X):
//  - same-address atomic chain ~184ns/op (r3).
//  - cross-XCD line sharing on scatter/append => no write-combining (r2/r7).
//    Fix: radix partition, per-WG exclusive output runs (r9).
//  - 1-output/thread dense = latency-stalled (r5) -> 4x4 register tiling.
//  - big LDS kills occupancy (r6) -> keep LDS <= ~34KB.
//  - r11+r12: gather ILP/instruction opts ~neutral -> gather is MEMORY-SYSTEM
//    bound: 410MB random 256B rows/GT from 25.6MB L3-resident buffer
//    (per-XCD L2 4MB can't hold it) ~ matches 85us at ~5TB/s L3 random.
//    Fix: bf16 message buffers (hwA/hwB) -> halve gathered bytes. Latent path
//    (hwL32/GO) stays f32 so bf16 noise is attenuated by @Wg/@Ws (~0.4 gain)
//    before reaching out: est added error ~1e-4 << 2^-8.
// Pipeline (10 dispatches):
//   hist | colscan | bscan | partition | build_csr(padded x8, sentinel n)
//   K0 : h0=x@Win+b -> {out = allbias + h0@Ws0, hwA=bf16((h0@Wg0)*dinv)}
//   GT1: gather_bf16(hwA)->h1 -> {out+=h1@Ws1, hwB=bf16((h1@Wg1)*dinv)}
//   GT2: gather_bf16(hwB)->h2 -> {out+=h2@Ws2, hwA=bf16((h2@Wg2)*dinv)}
//   GT3: gather_bf16(hwA)->h3 -> hwL32=f32((h3@Wl)*dinv)
//   GO : out += dinv * gather32_f32(hwL32)
// Identity: gcn(h)[v] = dinv[v] * sum_{s in nbr(v) u {v}} (hW*dinv)[s] + b

#define HID 64
#define LAT 32
#define PW 128         // partition WGs
#define CCAP 3456      // padded csr capacity per 128-node bucket

static inline int cdiv(long long a, long long b) { return (int)((a + b - 1) / b); }

// ---- bf16 helpers: channels packed ushort[2k]=lo, [2k+1]=hi of a uint ----
__device__ inline float bflo(unsigned u) { union { unsigned i; float f; } c; c.i = u << 16; return c.f; }
__device__ inline float bfhi(unsigned u) { union { unsigned i; float f; } c; c.i = u & 0xffff0000u; return c.f; }
__device__ inline unsigned packbf(float a, float b) {
    union { float f; unsigned i; } x, y;
    x.f = a; y.f = b;
    unsigned xa = x.i + 0x7fffu + ((x.i >> 16) & 1u);   // RNE
    unsigned yb = y.i + 0x7fffu + ((y.i >> 16) & 1u);
    return (xa >> 16) | (yb & 0xffff0000u);
}

// ---------------- CSR build: radix partition by dst>>7 ----------------

__global__ __launch_bounds__(256) void hist_kernel(const int* __restrict__ dst,
                                                   int* __restrict__ hist,
                                                   int E, int nb1, int chunk) {
    __shared__ int h[1024];
    int w = blockIdx.x, t = threadIdx.x;
    for (int i = t; i < nb1; i += 256) h[i] = 0;
    __syncthreads();
    int beg = w * chunk, end = min(E, beg + chunk);
    for (int e = beg + t; e < end; e += 256) atomicAdd(&h[dst[e] >> 7], 1);
    __syncthreads();
    for (int i = t; i < nb1; i += 256) hist[i * PW + w] = h[i];
}

__global__ __launch_bounds__(PW) void colscan_kernel(const int* __restrict__ hist,
                                                     int* __restrict__ colprefix,
                                                     int* __restrict__ btot) {
    __shared__ int s[PW];
    int b = blockIdx.x, t = threadIdx.x;
    int v = hist[b * PW + t];
    s[t] = v;
    __syncthreads();
    for (int off = 1; off < PW; off <<= 1) {
        int x = (t >= off) ? s[t - off] : 0;
        __syncthreads();
        s[t] += x;
        __syncthreads();
    }
    colprefix[b * PW + t] = s[t] - v;
    if (t == PW - 1) btot[b] = s[t];
}

__global__ __launch_bounds__(1024) void bscan_kernel(const int* __restrict__ btot,
                                                     int* __restrict__ bstart, int nb1, int E) {
    __shared__ int s[1024];
    int t = threadIdx.x;
    int v = (t < nb1) ? btot[t] : 0;
    s[t] = v;
    __syncthreads();
    for (int off = 1; off < 1024; off <<= 1) {
        int x = (t >= off) ? s[t - off] : 0;
        __syncthreads();
        s[t] += x;
        __syncthreads();
    }
    if (t < nb1) bstart[t] = s[t] - v;
    if (t == 0) bstart[nb1] = E;
}

__global__ __launch_bounds__(256) void partition_kernel(
        const int* __restrict__ src, const int* __restrict__ dst,
        const int* __restrict__ bstart, const int* __restrict__ colprefix,
        unsigned* __restrict__ bbuf, int E, int nb1, int chunk) {
    __shared__ int cur[1024];
    int w = blockIdx.x, t = threadIdx.x;
    for (int i = t; i < nb1; i += 256) cur[i] = bstart[i] + colprefix[i * PW + w];
    __syncthreads();
    int beg = w * chunk, end = min(E, beg + chunk);
    for (int e = beg + t; e < end; e += 256) {
        int s = src[e], d = dst[e];
        int pos = atomicAdd(&cur[d >> 7], 1);
        bbuf[pos] = ((unsigned)(d & 127) << 17) | (unsigned)s;
    }
}

// per-bucket: counts -> padded prefix (x8) -> scatter -> sentinel pad fill.
__global__ __launch_bounds__(256) void build_csr_kernel(
        const int* __restrict__ bstart, const unsigned* __restrict__ bbuf,
        int* __restrict__ csr, int* __restrict__ rowbeg, int* __restrict__ rowend,
        float* __restrict__ dinv, int n) {
    __shared__ int lcount[128], lpre[128], lcur[128];
    int b = blockIdx.x, t = threadIdx.x;
    int bst = bstart[b], bend = bstart[b + 1];
    int base = b * CCAP;

    if (t < 128) lcount[t] = 0;
    __syncthreads();
    for (int i = bst + t; i < bend; i += 256) atomicAdd(&lcount[bbuf[i] >> 17], 1);
    __syncthreads();
    if (t == 0) {
        int run = 0;
        for (int k = 0; k < 128; ++k) {
            lpre[k] = run;
            lcur[k] = run;
            run += (lcount[k] + 7) & ~7;
        }
    }
    __syncthreads();
    if (t < 128) {
        int v = (b << 7) + t;
        if (v < n) {
            int beg = base + lpre[t];
            rowbeg[v] = beg;
            rowend[v] = beg + ((lcount[t] + 7) & ~7);
            dinv[v] = rsqrtf((float)(lcount[t] + 1));
        }
    }
    for (int i = bst + t; i < bend; i += 256) {
        unsigned p = bbuf[i];
        int pos = base + atomicAdd(&lcur[p >> 17], 1);
        csr[pos] = (int)(p & 0x1FFFFu);
    }
    __syncthreads();
    if (t < 128) {
        int s = base + lpre[t] + lcount[t];
        int epad = base + lpre[t] + ((lcount[t] + 7) & ~7);
        for (int i = s; i < epad; ++i) csr[i] = n;  // sentinel -> zero message row
    }
}

// ---------------- K0: input layer, streamed-LDS x, 4x4 tiled ----------------

__global__ __launch_bounds__(256) void input_fused_kernel(
        const float* __restrict__ x, const float* __restrict__ Win,
        const float* __restrict__ bin, const float* __restrict__ Wg0,
        const float* __restrict__ Ws0, const float* __restrict__ dinv,
        const float* __restrict__ bl, const float* __restrict__ bs,
        unsigned short* __restrict__ hw, float* __restrict__ out, int n) {
    __shared__ float xs[2][64 * 33];
    __shared__ float h0[64 * 68];
    int t = threadIdx.x;
    int vbase = blockIdx.x * 64;
    int rg = t >> 4, lc = t & 15;

    if (blockIdx.x == 0 && t < 64) hw[(size_t)n * 64 + t] = 0;  // sentinel bf16 row

    int srow = t >> 3, scol = (t & 7) * 4;
    long long gr0 = vbase + srow;      if (gr0 >= n) gr0 = n - 1;
    long long gr1 = vbase + srow + 32; if (gr1 >= n) gr1 = n - 1;
    const float* gp0 = x + gr0 * 128 + scol;
    const float* gp1 = x + gr1 * 128 + scol;

    float4 p0 = *(const float4*)&gp0[0];
    float4 p1 = *(const float4*)&gp1[0];
    *(float4*)&xs[0][srow * 33 + scol] = p0;
    *(float4*)&xs[0][(srow + 32) * 33 + scol] = p1;
    __syncthreads();

    float4 b4 = *(const float4*)&bin[4 * lc];
    float4 a0 = b4, a1 = b4, a2 = b4, a3 = b4;
#pragma unroll
    for (int c = 0; c < 4; ++c) {
        if (c < 3) {
            p0 = *(const float4*)&gp0[(c + 1) * 32];
            p1 = *(const float4*)&gp1[(c + 1) * 32];
        }
        const float* xb = xs[c & 1];
        const float* wb = Win + (size_t)c * 32 * 64;
#pragma unroll
        for (int kk = 0; kk < 32; ++kk) {
            float4 w = *(const float4*)&wb[kk * 64 + 4 * lc];
            float x0 = xb[(rg * 4 + 0) * 33 + kk];
            float x1 = xb[(rg * 4 + 1) * 33 + kk];
            float x2 = xb[(rg * 4 + 2) * 33 + kk];
            float x3 = xb[(rg * 4 + 3) * 33 + kk];
            a0.x = fmaf(x0, w.x, a0.x); a0.y = fmaf(x0, w.y, a0.y);
            a0.z = fmaf(x0, w.z, a0.z); a0.w = fmaf(x0, w.w, a0.w);
            a1.x = fmaf(x1, w.x, a1.x); a1.y = fmaf(x1, w.y, a1.y);
            a1.z = fmaf(x1, w.z, a1.z); a1.w = fmaf(x1, w.w, a1.w);
            a2.x = fmaf(x2, w.x, a2.x); a2.y = fmaf(x2, w.y, a2.y);
            a2.z = fmaf(x2, w.z, a2.z); a2.w = fmaf(x2, w.w, a2.w);
            a3.x = fmaf(x3, w.x, a3.x); a3.y = fmaf(x3, w.y, a3.y);
            a3.z = fmaf(x3, w.z, a3.z); a3.w = fmaf(x3, w.w, a3.w);
        }
        if (c < 3) {
            *(float4*)&xs[(c + 1) & 1][srow * 33 + scol] = p0;
            *(float4*)&xs[(c + 1) & 1][(srow + 32) * 33 + scol] = p1;
            __syncthreads();
        }
    }
    *(float4*)&h0[(rg * 4 + 0) * 68 + 4 * lc] = a0;
    *(float4*)&h0[(rg * 4 + 1) * 68 + 4 * lc] = a1;
    *(float4*)&h0[(rg * 4 + 2) * 68 + 4 * lc] = a2;
    *(float4*)&h0[(rg * 4 + 3) * 68 + 4 * lc] = a3;
    __syncthreads();

    // Phase2a: hw = bf16((h0 @ Wg0) * dinv)
    {
        float4 c0, c1, c2, c3;
        c0 = c1 = c2 = c3 = make_float4(0.f, 0.f, 0.f, 0.f);
#pragma unroll 8
        for (int k = 0; k < 64; ++k) {
            float4 w = *(const float4*)&Wg0[k * 64 + 4 * lc];
            float x0 = h0[(rg * 4 + 0) * 68 + k];
            float x1 = h0[(rg * 4 + 1) * 68 + k];
            float x2 = h0[(rg * 4 + 2) * 68 + k];
            float x3 = h0[(rg * 4 + 3) * 68 + k];
            c0.x = fmaf(x0, w.x, c0.x); c0.y = fmaf(x0, w.y, c0.y);
            c0.z = fmaf(x0, w.z, c0.z); c0.w = fmaf(x0, w.w, c0.w);
            c1.x = fmaf(x1, w.x, c1.x); c1.y = fmaf(x1, w.y, c1.y);
            c1.z = fmaf(x1, w.z, c1.z); c1.w = fmaf(x1, w.w, c1.w);
            c2.x = fmaf(x2, w.x, c2.x); c2.y = fmaf(x2, w.y, c2.y);
            c2.z = fmaf(x2, w.z, c2.z); c2.w = fmaf(x2, w.w, c2.w);
            c3.x = fmaf(x3, w.x, c3.x); c3.y = fmaf(x3, w.y, c3.y);
            c3.z = fmaf(x3, w.z, c3.z); c3.w = fmaf(x3, w.w, c3.w);
        }
#pragma unroll
        for (int r = 0; r < 4; ++r) {
            int v = vbase + rg * 4 + r;
            if (v < n) {
                float di = dinv[v];
                float4 a = (r == 0) ? c0 : (r == 1) ? c1 : (r == 2) ? c2 : c3;
                uint2 o;
                o.x = packbf(a.x * di, a.y * di);
                o.y = packbf(a.z * di, a.w * di);
                *(uint2*)&hw[(size_t)v * 64 + 4 * lc] = o;
            }
        }
    }

    // Phase2b: out = (bl + sum bs) + h0 @ Ws0
    {
        int sg = t >> 3, sc = t & 7;
        float4 bb = *(const float4*)&bl[4 * sc];
        float4 q0 = *(const float4*)&bs[4 * sc];
        float4 q1 = *(const float4*)&bs[LAT + 4 * sc];
        float4 q2 = *(const float4*)&bs[2 * LAT + 4 * sc];
        bb.x += q0.x + q1.x + q2.x; bb.y += q0.y + q1.y + q2.y;
        bb.z += q0.z + q1.z + q2.z; bb.w += q0.w + q1.w + q2.w;
        float4 s0 = bb, s1 = bb;
#pragma unroll 8
        for (int k = 0; k < 64; ++k) {
            float4 w = *(const float4*)&Ws0[k * 32 + 4 * sc];
            float x0 = h0[(sg * 2 + 0) * 68 + k];
            float x1 = h0[(sg * 2 + 1) * 68 + k];
            s0.x = fmaf(x0, w.x, s0.x); s0.y = fmaf(x0, w.y, s0.y);
            s0.z = fmaf(x0, w.z, s0.z); s0.w = fmaf(x0, w.w, s0.w);
            s1.x = fmaf(x1, w.x, s1.x); s1.y = fmaf(x1, w.y, s1.y);
            s1.z = fmaf(x1, w.z, s1.z); s1.w = fmaf(x1, w.w, s1.w);
        }
#pragma unroll
        for (int r = 0; r < 2; ++r) {
            int v = vbase + sg * 2 + r;
            if (v < n)
                *(float4*)&out[(size_t)v * 32 + 4 * sc] = (r == 0) ? s0 : s1;
        }
    }
}

// ---------------- fused gather + transform, bf16 messages ----------------
// 64 nodes/block, 16 lanes/node (4 ch/lane, uint2=4 bf16 per gather load).

template <bool LAST>
__global__ __launch_bounds__(256) void gather_transform_kernel(
        const int* __restrict__ rowbeg, const int* __restrict__ rowend,
        const int* __restrict__ csr, const float* __restrict__ dinv,
        const unsigned short* __restrict__ hwin, const float* __restrict__ bias,
        const float* __restrict__ Wg, const float* __restrict__ Ws,
        unsigned short* __restrict__ hwout, float* __restrict__ hwout32,
        float* __restrict__ out, int n) {
    __shared__ float hL[64 * 68];
    int t = threadIdx.x;
    int vbase = blockIdx.x * 64;
    int ns = t >> 4, lc = t & 15;

    if (blockIdx.x == 0) {  // zero next sentinel row
        if (!LAST) { if (t < 64) hwout[(size_t)n * 64 + t] = 0; }
        else       { if (t < 32) hwout32[(size_t)n * 32 + t] = 0.f; }
    }

    float4 b4 = *(const float4*)&bias[4 * lc];
#pragma unroll
    for (int b = 0; b < 4; ++b) {
        int row = b * 16 + ns;
        int v = vbase + row;
        if (v < n) {
            int beg = rowbeg[v], end = rowend[v];
            float di = dinv[v];
            const unsigned short* basep = hwin + 4 * lc;
            uint2 sf = *(const uint2*)&basep[(size_t)v * 64];   // self (bf16)
            float4 acc;
            acc.x = bflo(sf.x); acc.y = bfhi(sf.x); acc.z = bflo(sf.y); acc.w = bfhi(sf.y);
            for (int e = beg; e < end; e += 8) {
                int4 ca = *(const int4*)&csr[e];
                int4 cb = *(const int4*)&csr[e + 4];
                uint2 g0 = *(const uint2*)&basep[(size_t)ca.x * 64];
                uint2 g1 = *(const uint2*)&basep[(size_t)ca.y * 64];
                uint2 g2 = *(const uint2*)&basep[(size_t)ca.z * 64];
                uint2 g3 = *(const uint2*)&basep[(size_t)ca.w * 64];
                uint2 g4 = *(const uint2*)&basep[(size_t)cb.x * 64];
                uint2 g5 = *(const uint2*)&basep[(size_t)cb.y * 64];
                uint2 g6 = *(const uint2*)&basep[(size_t)cb.z * 64];
                uint2 g7 = *(const uint2*)&basep[(size_t)cb.w * 64];
                acc.x += ((bflo(g0.x) + bflo(g1.x)) + (bflo(g2.x) + bflo(g3.x)))
                       + ((bflo(g4.x) + bflo(g5.x)) + (bflo(g6.x) + bflo(g7.x)));
                acc.y += ((bfhi(g0.x) + bfhi(g1.x)) + (bfhi(g2.x) + bfhi(g3.x)))
                       + ((bfhi(g4.x) + bfhi(g5.x)) + (bfhi(g6.x) + bfhi(g7.x)));
                acc.z += ((bflo(g0.y) + bflo(g1.y)) + (bflo(g2.y) + bflo(g3.y)))
                       + ((bflo(g4.y) + bflo(g5.y)) + (bflo(g6.y) + bflo(g7.y)));
                acc.w += ((bfhi(g0.y) + bfhi(g1.y)) + (bfhi(g2.y) + bfhi(g3.y)))
                       + ((bfhi(g4.y) + bfhi(g5.y)) + (bfhi(g6.y) + bfhi(g7.y)));
            }
            float4 h;
            h.x = di * acc.x + b4.x; h.x = h.x > 0.f ? h.x : 0.2f * h.x;
            h.y = di * acc.y + b4.y; h.y = h.y > 0.f ? h.y : 0.2f * h.y;
            h.z = di * acc.z + b4.z; h.z = h.z > 0.f ? h.z : 0.2f * h.z;
            h.w = di * acc.w + b4.w; h.w = h.w > 0.f ? h.w : 0.2f * h.w;
            *(float4*)&hL[row * 68 + 4 * lc] = h;
        }
    }
    __syncthreads();

    if (!LAST) {
        int rg = t >> 4;
        float4 c0, c1, c2, c3;
        c0 = c1 = c2 = c3 = make_float4(0.f, 0.f, 0.f, 0.f);
#pragma unroll 8
        for (int k = 0; k < 64; ++k) {
            float4 w = *(const float4*)&Wg[k * 64 + 4 * lc];
            float x0 = hL[(rg * 4 + 0) * 68 + k];
            float x1 = hL[(rg * 4 + 1) * 68 + k];
            float x2 = hL[(rg * 4 + 2) * 68 + k];
            float x3 = hL[(rg * 4 + 3) * 68 + k];
            c0.x = fmaf(x0, w.x, c0.x); c0.y = fmaf(x0, w.y, c0.y);
            c0.z = fmaf(x0, w.z, c0.z); c0.w = fmaf(x0, w.w, c0.w);
            c1.x = fmaf(x1, w.x, c1.x); c1.y = fmaf(x1, w.y, c1.y);
            c1.z = fmaf(x1, w.z, c1.z); c1.w = fmaf(x1, w.w, c1.w);
            c2.x = fmaf(x2, w.x, c2.x); c2.y = fmaf(x2, w.y, c2.y);
            c2.z = fmaf(x2, w.z, c2.z); c2.w = fmaf(x2, w.w, c2.w);
            c3.x = fmaf(x3, w.x, c3.x); c3.y = fmaf(x3, w.y, c3.y);
            c3.z = fmaf(x3, w.z, c3.z); c3.w = fmaf(x3, w.w, c3.w);
        }
#pragma unroll
        for (int r = 0; r < 4; ++r) {
            int v = vbase + rg * 4 + r;
            if (v < n) {
                float di = dinv[v];
                float4 a = (r == 0) ? c0 : (r == 1) ? c1 : (r == 2) ? c2 : c3;
                uint2 o;
                o.x = packbf(a.x * di, a.y * di);
                o.y = packbf(a.z * di, a.w * di);
                *(uint2*)&hwout[(size_t)v * 64 + 4 * lc] = o;
            }
        }

        int sg = t >> 3, sc = t & 7;
        float4 s0, s1;
        s0 = s1 = make_float4(0.f, 0.f, 0.f, 0.f);
#pragma unroll 8
        for (int k = 0; k < 64; ++k) {
            float4 w = *(const float4*)&Ws[k * 32 + 4 * sc];
            float x0 = hL[(sg * 2 + 0) * 68 + k];
            float x1 = hL[(sg * 2 + 1) * 68 + k];
            s0.x = fmaf(x0, w.x, s0.x); s0.y = fmaf(x0, w.y, s0.y);
            s0.z = fmaf(x0, w.z, s0.z); s0.w = fmaf(x0, w.w, s0.w);
            s1.x = fmaf(x1, w.x, s1.x); s1.y = fmaf(x1, w.y, s1.y);
            s1.z = fmaf(x1, w.z, s1.z); s1.w = fmaf(x1, w.w, s1.w);
        }
#pragma unroll
        for (int r = 0; r < 2; ++r) {
            int v = vbase + sg * 2 + r;
            if (v < n) {
                float4 a = (r == 0) ? s0 : s1;
                float4* op = (float4*)(out + (size_t)v * 32 + 4 * sc);
                float4 o = *op;
                o.x += a.x; o.y += a.y; o.z += a.z; o.w += a.w;
                *op = o;
            }
        }
    } else {
        int sg = t >> 3, sc = t & 7;
        float4 s0, s1;
        s0 = s1 = make_float4(0.f, 0.f, 0.f, 0.f);
#pragma unroll 8
        for (int k = 0; k < 64; ++k) {
            float4 w = *(const float4*)&Ws[k * 32 + 4 * sc];  // Ws == Wl
            float x0 = hL[(sg * 2 + 0) * 68 + k];
            float x1 = hL[(sg * 2 + 1) * 68 + k];
            s0.x = fmaf(x0, w.x, s0.x); s0.y = fmaf(x0, w.y, s0.y);
            s0.z = fmaf(x0, w.z, s0.z); s0.w = fmaf(x0, w.w, s0.w);
            s1.x = fmaf(x1, w.x, s1.x); s1.y = fmaf(x1, w.y, s1.y);
            s1.z = fmaf(x1, w.z, s1.z); s1.w = fmaf(x1, w.w, s1.w);
        }
#pragma unroll
        for (int r = 0; r < 2; ++r) {
            int v = vbase + sg * 2 + r;
            if (v < n) {
                float di = dinv[v];
                float4 a = (r == 0) ? s0 : s1;
                a.x *= di; a.y *= di; a.z *= di; a.w *= di;
                *(float4*)&hwout32[(size_t)v * 32 + 4 * sc] = a;
            }
        }
    }
}

// ---------------- final gather into output (f32, 32 ch, 8 lanes/node) ----------------

__global__ __launch_bounds__(256) void gather_out_kernel(
        const int* __restrict__ rowbeg, const int* __restrict__ rowend,
        const int* __restrict__ csr, const float* __restrict__ dinv,
        const float* __restrict__ hwl, float* __restrict__ out, int n) {
    int t = threadIdx.x;
    int lr = t >> 3, lc = t & 7;
    int v = blockIdx.x * 32 + lr;
    if (v >= n) return;
    int beg = rowbeg[v], end = rowend[v];
    float4 acc = *(const float4*)&hwl[(size_t)v * 32 + 4 * lc];
    const float* base = hwl + 4 * lc;
    for (int e = beg; e < end; e += 8) {
        int4 ca = *(const int4*)&csr[e];
        int4 cb = *(const int4*)&csr[e + 4];
        float4 g0 = *(const float4*)&base[(size_t)ca.x * 32];
        float4 g1 = *(const float4*)&base[(size_t)ca.y * 32];
        float4 g2 = *(const float4*)&base[(size_t)ca.z * 32];
        float4 g3 = *(const float4*)&base[(size_t)ca.w * 32];
        float4 g4 = *(const float4*)&base[(size_t)cb.x * 32];
        float4 g5 = *(const float4*)&base[(size_t)cb.y * 32];
        float4 g6 = *(const float4*)&base[(size_t)cb.z * 32];
        float4 g7 = *(const float4*)&base[(size_t)cb.w * 32];
        acc.x += ((g0.x + g1.x) + (g2.x + g3.x)) + ((g4.x + g5.x) + (g6.x + g7.x));
        acc.y += ((g0.y + g1.y) + (g2.y + g3.y)) + ((g4.y + g5.y) + (g6.y + g7.y));
        acc.z += ((g0.z + g1.z) + (g2.z + g3.z)) + ((g4.z + g5.z) + (g6.z + g7.z));
        acc.w += ((g0.w + g1.w) + (g2.w + g3.w)) + ((g4.w + g5.w) + (g6.w + g7.w));
    }
    float di = dinv[v];
    float4* op = (float4*)(out + (size_t)v * 32 + 4 * lc);
    float4 o = *op;
    o.x += di * acc.x; o.y += di * acc.y; o.z += di * acc.z; o.w += di * acc.w;
    *op = o;
}

// ---------------- launch ----------------

extern "C" void kernel_launch(void* const* d_in, const int* in_sizes, int n_in,
                              void* d_out, int out_size, void* d_ws, size_t ws_size,
                              hipStream_t stream) {
    const float* x    = (const float*)d_in[0];
    const int*   ei   = (const int*)d_in[1];
    const float* W_in = (const float*)d_in[2];
    const float* b_in = (const float*)d_in[3];
    const float* Wg   = (const float*)d_in[4];  // [3][64][64]
    const float* bg   = (const float*)d_in[5];  // [3][64]
    const float* Ws   = (const float*)d_in[6];  // [3][64][32]
    const float* bs   = (const float*)d_in[7];  // [3][32]
    const float* Wl   = (const float*)d_in[8];  // [64][32]
    const float* bl   = (const float*)d_in[9];  // [32]

    const int N = in_sizes[0] / 128;
    const int E = in_sizes[1] / 2;
    const int nb1 = cdiv(N, 128);
    const int chunk = cdiv(E, PW);
    const int* srcp = ei;
    const int* dstp = ei + E;

    char* p = (char*)d_ws;
    unsigned short* hwA   = (unsigned short*)p; p += ((size_t)N + 1) * HID * 2;
    unsigned short* hwB   = (unsigned short*)p; p += ((size_t)N + 1) * HID * 2;
    float*    hwl32    = (float*)p;    p += ((size_t)N + 1) * LAT * 4;
    unsigned* bbuf     = (unsigned*)p; p += (size_t)E * 4;
    int*      csr      = (int*)p;      p += (size_t)nb1 * CCAP * 4;
    int*      rowbeg   = (int*)p;      p += (size_t)N * 4;
    int*      rowend   = (int*)p;      p += (size_t)N * 4;
    float*    dinv     = (float*)p;    p += (size_t)N * 4;
    int*      hist     = (int*)p;      p += (size_t)nb1 * PW * 4;
    int*      colpre   = (int*)p;      p += (size_t)nb1 * PW * 4;
    int*      btot     = (int*)p;      p += (size_t)nb1 * 4;
    int*      bstart   = (int*)p;      p += ((size_t)nb1 + 1) * 4;
    float*    out      = (float*)d_out;

    const int B = 256;

    hist_kernel<<<PW, B, 0, stream>>>(dstp, hist, E, nb1, chunk);
    colscan_kernel<<<nb1, PW, 0, stream>>>(hist, colpre, btot);
    bscan_kernel<<<1, 1024, 0, stream>>>(btot, bstart, nb1, E);
    partition_kernel<<<PW, B, 0, stream>>>(srcp, dstp, bstart, colpre, bbuf, E, nb1, chunk);
    build_csr_kernel<<<nb1, B, 0, stream>>>(bstart, bbuf, csr, rowbeg, rowend, dinv, N);

    input_fused_kernel<<<cdiv(N, 64), B, 0, stream>>>(
        x, W_in, b_in, Wg, Ws, dinv, bl, bs, hwA, out, N);

    gather_transform_kernel<false><<<cdiv(N, 64), B, 0, stream>>>(
        rowbeg, rowend, csr, dinv, hwA, bg, Wg + 4096, Ws + 2048, hwB, nullptr, out, N);

    gather_transform_kernel<false><<<cdiv(N, 64), B, 0, stream>>>(
        rowbeg, rowend, csr, dinv, hwB, bg + 64, Wg + 8192, Ws + 4096, hwA, nullptr, out, N);

    gather_transform_kernel<true><<<cdiv(N, 64), B, 0, stream>>>(
        rowbeg, rowend, csr, dinv, hwA, bg + 128, nullptr, Wl, nullptr, hwl32, nullptr, N);

    gather_out_kernel<<<cdiv(N, 32), B, 0, stream>>>(rowbeg, rowend, csr, dinv, hwl32, out, N);
}